// Round 7
// baseline (1201.469 us; speedup 1.0000x reference)
//
#include <hip/hip_runtime.h>
#include <cstdint>
#include <cstddef>

typedef unsigned int u32;
typedef unsigned long long u64;
typedef __attribute__((ext_vector_type(8))) short s8v;   // 8 bf16 (4 VGPRs)
typedef __attribute__((ext_vector_type(4))) float f4v;   // MFMA C/D

#define B_   2
#define L_   2048
#define D_   1024
#define NH_  16
#define KVH_ 8
#define DH_  64
#define TOPK_ 1024

#define MFMA16(a, b, c) __builtin_amdgcn_mfma_f32_16x16x32_bf16(a, b, c, 0, 0, 0)

// order-preserving float->uint key (descending float == descending uint)
__device__ __forceinline__ u32 fkey(float s) {
    u32 b = __float_as_uint(s);
    return b ^ ((u32)((int)b >> 31) | 0x80000000u);
}
// exact inverse of fkey
__device__ __forceinline__ float fkeyinv(u32 k) {
    u32 b = (k & 0x80000000u) ? (k ^ 0x80000000u) : ~k;
    return __uint_as_float(b);
}
// fp32 -> bf16 round-to-nearest-even, as raw ushort
__device__ __forceinline__ unsigned short bf16rne(float x) {
    u32 u = __float_as_uint(x);
    u32 r = (u + 0x7FFFu + ((u >> 16) & 1u)) >> 16;
    return (unsigned short)r;
}
__device__ __forceinline__ float bf2f(unsigned short h) {
    return __uint_as_float((u32)h << 16);
}

// ---------------------------------------------------------------------------
// W [K][N] fp32 -> WtH/WtL [N][K] bf16 hi/lo (transpose + split). grid (K/64, N/64)
// ---------------------------------------------------------------------------
__global__ __launch_bounds__(256) void prep_wt(const float* __restrict__ W,
                                               unsigned short* __restrict__ WtH,
                                               unsigned short* __restrict__ WtL,
                                               int K, int N) {
    __shared__ float tile[64 * 65];
    int k0 = blockIdx.x * 64, n0 = blockIdx.y * 64;
    int t = threadIdx.x;
#pragma unroll
    for (int i = 0; i < 16; ++i) {
        int idx = t + i * 256;
        int kk = idx >> 6, nn = idx & 63;
        tile[kk * 65 + nn] = W[(size_t)(k0 + kk) * N + n0 + nn];
    }
    __syncthreads();
#pragma unroll
    for (int i = 0; i < 16; ++i) {
        int idx = t + i * 256;
        int nn = idx >> 6, kk = idx & 63;
        float x = tile[kk * 65 + nn];
        unsigned short hi = bf16rne(x);
        unsigned short lo = bf16rne(x - bf2f(hi));
        WtH[(size_t)(n0 + nn) * K + k0 + kk] = hi;
        WtL[(size_t)(n0 + nn) * K + k0 + kk] = lo;
    }
}

// ---------------------------------------------------------------------------
// MFMA GEMM: C[M][N] fp32 = A[M][K] fp32 @ Wt([N][K] bf16 hi/lo), 3-term hi/lo.
// BM=128, BN=128, BK=32; 256 threads (4 waves, 2x2 of 64x64). grid (M/128, N/128)
// XCD-chunked block swizzle (nwg%8==0 for all 3 shapes).
// ---------------------------------------------------------------------------
__global__ __launch_bounds__(256) void gemm_mfma(
    const float* __restrict__ A,
    const unsigned short* __restrict__ Wh,
    const unsigned short* __restrict__ Wl,
    float* __restrict__ C, int K, int N) {
    __shared__ __align__(16) unsigned short lAh[128 * 40];
    __shared__ __align__(16) unsigned short lAl[128 * 40];
    __shared__ __align__(16) unsigned short lBh[128 * 40];
    __shared__ __align__(16) unsigned short lBl[128 * 40];
    const int t = threadIdx.x, lane = t & 63, w = t >> 6;
    const int quad = lane >> 4, col = lane & 15;
    const int wm = w >> 1, wn = w & 1;
    const int nwg = gridDim.x * gridDim.y;
    const int lin = blockIdx.y * gridDim.x + blockIdx.x;
    const int swz = (lin & 7) * (nwg >> 3) + (lin >> 3);
    const int bx = swz % gridDim.x, by = swz / gridDim.x;
    const int m0 = bx * 128, n0 = by * 128;
    const int sr = t >> 1, sk = (t & 1) * 16;

    f4v acc[4][4];
#pragma unroll
    for (int i = 0; i < 4; ++i)
#pragma unroll
        for (int j = 0; j < 4; ++j) acc[i][j] = (f4v){0.f, 0.f, 0.f, 0.f};

    for (int k0 = 0; k0 < K; k0 += 32) {
        const float* ap = A + (size_t)(m0 + sr) * K + k0 + sk;
        float4 a0 = *(const float4*)(ap);
        float4 a1 = *(const float4*)(ap + 4);
        float4 a2 = *(const float4*)(ap + 8);
        float4 a3 = *(const float4*)(ap + 12);
        s8v bh0 = *(const s8v*)(Wh + (size_t)(n0 + sr) * K + k0 + sk);
        s8v bh1 = *(const s8v*)(Wh + (size_t)(n0 + sr) * K + k0 + sk + 8);
        s8v bl0 = *(const s8v*)(Wl + (size_t)(n0 + sr) * K + k0 + sk);
        s8v bl1 = *(const s8v*)(Wl + (size_t)(n0 + sr) * K + k0 + sk + 8);
        float av[16] = {a0.x, a0.y, a0.z, a0.w, a1.x, a1.y, a1.z, a1.w,
                        a2.x, a2.y, a2.z, a2.w, a3.x, a3.y, a3.z, a3.w};
        union { s8v v; unsigned short u[8]; } ah_[2], al_[2];
#pragma unroll
        for (int i = 0; i < 16; ++i) {
            unsigned short hi = bf16rne(av[i]);
            ah_[i >> 3].u[i & 7] = hi;
            al_[i >> 3].u[i & 7] = bf16rne(av[i] - bf2f(hi));
        }
        __syncthreads();
        *(s8v*)&lAh[sr * 40 + sk]     = ah_[0].v;
        *(s8v*)&lAh[sr * 40 + sk + 8] = ah_[1].v;
        *(s8v*)&lAl[sr * 40 + sk]     = al_[0].v;
        *(s8v*)&lAl[sr * 40 + sk + 8] = al_[1].v;
        *(s8v*)&lBh[sr * 40 + sk]     = bh0;
        *(s8v*)&lBh[sr * 40 + sk + 8] = bh1;
        *(s8v*)&lBl[sr * 40 + sk]     = bl0;
        *(s8v*)&lBl[sr * 40 + sk + 8] = bl1;
        __syncthreads();
        s8v amh[4], aml[4], bnh[4], bnl[4];
#pragma unroll
        for (int mt = 0; mt < 4; ++mt) {
            amh[mt] = *(s8v*)&lAh[(wm * 64 + mt * 16 + col) * 40 + quad * 8];
            aml[mt] = *(s8v*)&lAl[(wm * 64 + mt * 16 + col) * 40 + quad * 8];
        }
#pragma unroll
        for (int nt = 0; nt < 4; ++nt) {
            bnh[nt] = *(s8v*)&lBh[(wn * 64 + nt * 16 + col) * 40 + quad * 8];
            bnl[nt] = *(s8v*)&lBl[(wn * 64 + nt * 16 + col) * 40 + quad * 8];
        }
#pragma unroll
        for (int mt = 0; mt < 4; ++mt)
#pragma unroll
            for (int nt = 0; nt < 4; ++nt) {
                acc[mt][nt] = MFMA16(amh[mt], bnh[nt], acc[mt][nt]);
                acc[mt][nt] = MFMA16(amh[mt], bnl[nt], acc[mt][nt]);
                acc[mt][nt] = MFMA16(aml[mt], bnh[nt], acc[mt][nt]);
            }
    }
#pragma unroll
    for (int mt = 0; mt < 4; ++mt)
#pragma unroll
        for (int nt = 0; nt < 4; ++nt)
#pragma unroll
            for (int r = 0; r < 4; ++r)
                C[(size_t)(m0 + wm * 64 + mt * 16 + quad * 4 + r) * N +
                  n0 + wn * 64 + nt * 16 + col] = acc[mt][nt][r];
}

// ---------------------------------------------------------------------------
// RoPE on Q, in place. Layout [b][l][h][d].
// ---------------------------------------------------------------------------
__global__ __launch_bounds__(256) void rope_q(float* __restrict__ Q,
                                              const int* __restrict__ pos) {
    int tid = blockIdx.x * 256 + threadIdx.x;
    int dl = tid & 31;
    int h  = (tid >> 5) & 15;
    int l  = (tid >> 9) & 2047;
    int b  = tid >> 20;
    size_t base = ((size_t)(b * L_ + l) * NH_ + h) * DH_;
    float x1 = Q[base + dl];
    float x2 = Q[base + dl + 32];
    float p = (float)pos[b * L_ + l];
    float invf = (float)pow(10000.0, -(double)dl / 32.0);
    float a = p * invf;
    float s, c;
    sincosf(a, &s, &c);
    Q[base + dl]      = x1 * c - x2 * s;
    Q[base + dl + 32] = x2 * c + x1 * s;
}

// ---------------------------------------------------------------------------
// RoPE on K + hi/lo bf16 split, layout [b][kvh][l][d]
// ---------------------------------------------------------------------------
__global__ __launch_bounds__(256) void prep_k(const float* __restrict__ Kraw,
                                              unsigned short* __restrict__ KHp,
                                              unsigned short* __restrict__ KLp,
                                              const int* __restrict__ pos) {
    int tid = blockIdx.x * 256 + threadIdx.x;
    int d   = tid & 63;
    int l   = (tid >> 6) & 2047;
    int kvh = (tid >> 17) & 7;
    int b   = tid >> 20;
    size_t src = ((size_t)(b * L_ + l) * KVH_ + kvh) * DH_;
    float x  = Kraw[src + d];
    int dp   = (d < 32) ? d + 32 : d - 32;
    float xp = Kraw[src + dp];
    float p = (float)pos[b * L_ + l];
    int i = d & 31;
    float invf = (float)pow(10000.0, -(double)i / 32.0);
    float a = p * invf;
    float s, c;
    sincosf(a, &s, &c);
    float out = (d < 32) ? (x * c - xp * s) : (x * c + xp * s);
    unsigned short hi = bf16rne(out);
    unsigned short lo = bf16rne(out - bf2f(hi));
    size_t dst = ((size_t)(b * KVH_ + kvh) * L_ + l) * DH_ + d;
    KHp[dst] = hi;
    KLp[dst] = lo;
}

// ---------------------------------------------------------------------------
// V transpose to bf16: Vraw[b][l][kvh][d] -> VT[b][kvh][d][l]
// ---------------------------------------------------------------------------
__global__ __launch_bounds__(256) void prep_v(const float* __restrict__ Vraw,
                                              unsigned short* __restrict__ VTp) {
    __shared__ float tile[64 * 65];
    int bid = blockIdx.x;
    int lb  = bid & 31;
    int kvh = (bid >> 5) & 7;
    int b   = bid >> 8;
    int l0  = lb * 64;
    int t   = threadIdx.x;
#pragma unroll
    for (int i = 0; i < 16; ++i) {
        int idx = t + i * 256;
        int ll = idx >> 6, d = idx & 63;
        tile[ll * 65 + d] = Vraw[((size_t)(b * L_ + l0 + ll) * KVH_ + kvh) * DH_ + d];
    }
    __syncthreads();
#pragma unroll
    for (int i = 0; i < 16; ++i) {
        int idx = t + i * 256;
        int d = idx >> 6, ll = idx & 63;
        VTp[((size_t)(b * KVH_ + kvh) * DH_ + d) * L_ + l0 + ll] = bf16rne(tile[ll * 65 + d]);
    }
}

// ---------------------------------------------------------------------------
// Fused sparse attention, R15: 2-blocks/CU occupancy via organic register diet.
// Post-R14 ledger: time tracks resident waves / block overlap, not cache
// (R12), not conflicts (R10), not spill traffic (R13). R14 sits at 1 block/CU
// (occ 47%): 2 blocks fit threads (2048) and LDS (151<160KB), so the limiter
// is unified VGPR+AGPR > 64 (8 waves/SIMD needs <=64; arch-VGPR 52 excludes
// AGPR accs + T-hold + V-prefetch). Deficit is small, unlike R13's forced 85
// cap at ~110 organic (-> spill storm). Diet: (a) drop T[4] hold -> jp1
// immediate per-tj writes (2-block skew now provides the overlap the hold
// bought); (b) drop V kc0 prefetch (its 16 regs were live across the P-write
// peak where uk[32]-as-e also lives); (c) __launch_bounds__(1024, 8) pins 64.
// Peak live est ~58. Falsifier: occ stays 47% at VGPR<=64, or WRITE_SIZE
// rises (spills) -> revert diet, split kernel instead.
// ---------------------------------------------------------------------------
__global__ __launch_bounds__(1024, 8) void attn(
    const float* __restrict__ QR,
    const unsigned short* __restrict__ KH,
    const unsigned short* __restrict__ KL,
    const unsigned short* __restrict__ VT,
    float* __restrict__ AO) {

    extern __shared__ __align__(16) unsigned char dynsm[];
    float* Sc = (float*)dynsm;                               // [16*1044] 66816B
    unsigned short* Pc = (unsigned short*)dynsm;             // [16*2072] 66304B
    u32* hist = (u32*)dynsm;                                 // [16*1024] 65536B
    float* qtile  = (float*)(dynsm + 66816);                 // [16*68] 4352B
    float* outred = (float*)(dynsm + 66816 + 4352);          // [16*68] 4352B

    const int t = threadIdx.x;
    const int lane = t & 63, w = t >> 6;            // w in [0,16)
    const int quad = lane >> 4, col = lane & 15;
    // XCD-chunked remap (bijective: 4096 % 8 == 0)
    const int bid0 = blockIdx.x;
    const int bid  = (bid0 & 7) * 512 + (bid0 >> 3);
    const int l0  = (bid & 255) * 8;
    const int kvh = (bid >> 8) & 7;
    const int b   = bid >> 11;

    // ---- load Q tile (16 rows = 8 l-pos x heads {2kvh, 2kvh+1}); zero outred
    if (t < 256) {
        int q = t >> 4, d4 = (t & 15) * 4;
        *(float4*)&qtile[q * 68 + d4] =
            *(const float4*)(QR + ((size_t)((b * L_ + l0 + (q & 7)) * NH_ +
                                            kvh * 2 + (q >> 3))) * DH_ + d4);
    }
    outred[t] = 0.f;
    if (t < 64) outred[1024 + t] = 0.f;
    __syncthreads();

    // ---- build A-frags (hi/lo): A[m=col][k=ks*32+quad*8+i]; all 16 rows real
    union FR { s8v v; unsigned short u[8]; };
    FR ah[2], al[2];
#pragma unroll
    for (int ks = 0; ks < 2; ++ks)
#pragma unroll
        for (int i = 0; i < 8; ++i) {
            float x = qtile[col * 68 + ks * 32 + quad * 8 + i];
            unsigned short hi = bf16rne(x);
            ah[ks].u[i] = hi;
            al[ks].u[i] = bf16rne(x - bf2f(hi));
        }

    // ---- QK^T + transpose, 2 J-passes of 1024 cols (wave slice = 64 cols/jp)
    const size_t slabK = (size_t)(b * KVH_ + kvh) * L_ * DH_;
    const unsigned short* khp = KH + slabK;
    const unsigned short* klp = KL + slabK;
    u32 uk[32];   // row-w keys; elem i: j = 1024*(i>>4) + 64*(i&15) + lane

    auto qk_tj = [&](int jp, int tj) -> f4v {
        int j0 = jp * 1024 + w * 64 + tj * 16;
        const unsigned short* kh8 = khp + (size_t)(j0 + col) * 64 + quad * 8;
        const unsigned short* kl8 = klp + (size_t)(j0 + col) * 64 + quad * 8;
        s8v bh0 = *(const s8v*)(kh8);
        s8v bh1 = *(const s8v*)(kh8 + 32);
        s8v bl0 = *(const s8v*)(kl8);
        s8v bl1 = *(const s8v*)(kl8 + 32);
        f4v c = {0.f, 0.f, 0.f, 0.f};
        c = MFMA16(ah[0].v, bh0, c);
        c = MFMA16(al[0].v, bh0, c);
        c = MFMA16(ah[0].v, bl0, c);
        c = MFMA16(ah[1].v, bh1, c);
        c = MFMA16(al[1].v, bh1, c);
        c = MFMA16(ah[1].v, bl1, c);
        return c * 0.125f;               // DH^-0.5
    };
    auto sc_put = [&](int tj, f4v Sv) {  // all quads: rows q = quad*4+r
#pragma unroll
        for (int r = 0; r < 4; ++r)
            Sc[(quad * 4 + r) * 1044 + w * 64 + tj * 16 + col] = Sv[r];
    };

#pragma unroll
    for (int jp = 0; jp < 2; ++jp) {
        if (jp) __syncthreads();         // (B) all Sc(jp0) reads done
#pragma unroll
        for (int tj = 0; tj < 4; ++tj) sc_put(tj, qk_tj(jp, tj));
        __syncthreads();                 // (A)/(C) Sc(jp) complete
#pragma unroll
        for (int i2 = 0; i2 < 16; ++i2)
            uk[jp * 16 + i2] = fkey(Sc[w * 1044 + i2 * 64 + lane]);
    }
    __syncthreads();                     // (D) Sc reads done; hist region free

    // ---- order-preserving key normalization: spread radix digits.
    u32 ulo = 0xFFFFFFFFu, uhi = 0u;
#pragma unroll
    for (int i = 0; i < 32; ++i) {
        u32 u = uk[i];
        ulo = (u < ulo) ? u : ulo;
        uhi = (u > uhi) ? u : uhi;
    }
    for (int off = 1; off < 64; off <<= 1) {
        u32 ol = (u32)__shfl_xor((int)ulo, off);
        u32 oh = (u32)__shfl_xor((int)uhi, off);
        ulo = (ol < ulo) ? ol : ulo;
        uhi = (oh > uhi) ? oh : uhi;
    }
    const float mrow = fkeyinv(uhi);     // row max, free from the reduction
    const int sh = __clz((int)((uhi - ulo) | 1u));   // 0..31
#pragma unroll
    for (int i = 0; i < 32; ++i) uk[i] = (uk[i] - ulo) << sh;

    // ---- wave-local exact top-1024: radix with wave-uniform early-exit.
    // Digit d, replica lane&3 at hq[(d&3)*256 + (d>>2)*4 + (lane&3)].
    u32 pf = 0u, kq = (u32)TOPK_, ng = 0u, geq = 0u;
    u32* hq = &hist[w * 1024];
    const int rep = lane & 3;
    for (int pass = 0; pass < 4; ++pass) {
        int shift = 24 - 8 * pass;
#pragma unroll
        for (int i = 0; i < 4; ++i)
            *(uint4*)&hq[i * 256 + lane * 4] = make_uint4(0u, 0u, 0u, 0u);
        u32 pm = pass ? (0xFFFFFFFFu << (shift + 8)) : 0u;
#pragma unroll
        for (int i = 0; i < 32; ++i) {
            u32 u = uk[i];
            if ((u & pm) == pf) {
                u32 d = (u >> shift) & 255u;
                atomicAdd(&hq[(d & 3) * 256 + (d >> 2) * 4 + rep], 1u);
            }
        }
        // reads may-alias the atomics => real ds ops, wave-ordered.
        u32 hb_[4];
        u32 s4 = 0u;
#pragma unroll
        for (int bb = 0; bb < 4; ++bb) {
            uint4 hv = *(const uint4*)&hq[bb * 256 + lane * 4];
            hb_[bb] = hv.x + hv.y + hv.z + hv.w;
            s4 += hb_[bb];
        }
        u32 v = s4;
        for (int off = 1; off < 64; off <<= 1) {
            u32 tmp = __shfl_down(v, off);
            if (lane + off < 64) v += tmp;
        }
        u32 g = v - s4;                  // # keys with digit > 4*lane+3
        u32 mydig = 0u, myk = 0u, myng = 0u, myhb = 0u;
        bool found = false;
#pragma unroll
        for (int bb = 3; bb >= 0; --bb) {
            u32 hb = hb_[bb];
            if (hb && g < kq && kq <= g + hb) {   // true for exactly one (lane,bb)
                found = true;
                mydig = (u32)(4 * lane + bb);
                myk   = kq - g;
                myng  = ng + g;
                myhb  = hb;
            }
            g += hb;
        }
        u64 fm = __ballot(found);
        int src = (int)__builtin_ctzll(fm);
        pf |= ((u32)__shfl((int)mydig, src)) << shift;
        kq  = (u32)__shfl((int)myk,  src);
        ng  = (u32)__shfl((int)myng, src);
        u32 hbs = (u32)__shfl((int)myhb, src);
        if (kq == hbs) { geq = 1u; break; }  // whole bucket selected: exact
    }

    // ---- selection mask (wave-local, register state)
    const u32 uth = pf;
    u32 selm = 0u;
    if (geq) {
#pragma unroll
        for (int i = 0; i < 32; ++i)
            if (uk[i] >= uth) selm |= 1u << i;
    } else {
        const u32 quota = (u32)TOPK_ - ng;
        u32 eqm = 0u;
#pragma unroll
        for (int i = 0; i < 32; ++i) {
            u32 u = uk[i];
            if (u > uth) selm |= 1u << i;
            else if (u == uth) eqm |= 1u << i;
        }
        u32 ec = (u32)__builtin_popcount(eqm);
        for (int off = 1; off < 64; off <<= 1) ec += __shfl_xor(ec, off);
        if (ec == quota) {
            selm |= eqm;                 // common case: take all tied entries
        } else {                         // rare: rank ties by lowest index j
            u32 base = 0;
            u64 lmask = ((u64)1 << lane) - 1;
#pragma unroll
            for (int i = 0; i < 32; ++i) {
                u64 mm = __ballot((eqm >> i) & 1u);
                if ((eqm >> i) & 1u) {
                    u32 rk = base + (u32)__builtin_popcountll(mm & lmask);
                    if (rk < quota) selm |= 1u << i;
                }
                base += (u32)__builtin_popcountll(mm);
            }
        }
    }

    // ---- wave-local softmax (mrow from the min/max reduction), invZ in P
    float z = 0.f;
#pragma unroll
    for (int i = 0; i < 32; ++i) {
        float vv = fkeyinv((uk[i] >> sh) + ulo);          // exact inverse
        float e = ((selm >> i) & 1u) ? __expf(vv - mrow) : 0.f;
        uk[i] = __float_as_uint(e);      // keys dead; reuse as e-storage
        z += e;
    }
    for (int off = 1; off < 64; off <<= 1) z += __shfl_xor(z, off);
    float invZ = 1.0f / z;

    // ---- P -> Pc (bf16, invZ folded); row w
    __syncthreads();                     // hist use done; Pc region free
#pragma unroll
    for (int i = 0; i < 32; ++i) {
        unsigned short pv16 = bf16rne(__uint_as_float(uk[i]) * invZ);
        Pc[w * 2072 + 1024 * (i >> 4) + 64 * (i & 15) + lane] = pv16;
    }
    __syncthreads();                     // all P rows written

    // ---- PV via MFMA; wave w covers j in [128w, 128w+128) in 4 sub-chunks
    const unsigned short* vt = VT + (size_t)(b * KVH_ + kvh) * DH_ * L_;
    f4v acc0 = {0.f, 0.f, 0.f, 0.f}, acc1 = acc0, acc2 = acc0, acc3 = acc0;
#pragma unroll
    for (int kc = 0; kc < 4; ++kc) {
        int jb = w * 128 + kc * 32 + quad * 8;
        s8v ap = *(const s8v*)&Pc[col * 2072 + jb];
        s8v v0 = *(const s8v*)(vt + (size_t)( 0 + col) * L_ + jb);
        s8v v1 = *(const s8v*)(vt + (size_t)(16 + col) * L_ + jb);
        s8v v2 = *(const s8v*)(vt + (size_t)(32 + col) * L_ + jb);
        s8v v3 = *(const s8v*)(vt + (size_t)(48 + col) * L_ + jb);
        acc0 = MFMA16(ap, v0, acc0);
        acc1 = MFMA16(ap, v1, acc1);
        acc2 = MFMA16(ap, v2, acc2);
        acc3 = MFMA16(ap, v3, acc3);
    }

    // ---- cross-wave PV reduction (all 16 rows live) + store
#pragma unroll
    for (int r = 0; r < 4; ++r) {
        atomicAdd(&outred[(quad * 4 + r) * 68 +  0 + col], acc0[r]);
        atomicAdd(&outred[(quad * 4 + r) * 68 + 16 + col], acc1[r]);
        atomicAdd(&outred[(quad * 4 + r) * 68 + 32 + col], acc2[r]);
        atomicAdd(&outred[(quad * 4 + r) * 68 + 48 + col], acc3[r]);
    }
    __syncthreads();
    if (t < 256) {
        int q = t >> 4, d4 = (t & 15) * 4;
        float4 o = *(float4*)&outred[q * 68 + d4];
        *(float4*)(AO + ((size_t)((b * L_ + l0 + (q & 7)) * NH_ +
                                  kvh * 2 + (q >> 3))) * DH_ + d4) = o;
    }
}

// ---------------------------------------------------------------------------
extern "C" void kernel_launch(void* const* d_in, const int* in_sizes, int n_in,
                              void* d_out, int out_size, void* d_ws, size_t ws_size,
                              hipStream_t stream) {
    const float* hs = (const float*)d_in[0];
    const float* wq = (const float*)d_in[1];
    const float* wk = (const float*)d_in[2];
    const float* wv = (const float*)d_in[3];
    const float* wo = (const float*)d_in[4];
    const int*  pos = (const int*)d_in[5];

    float* ws = (float*)d_ws;
    const size_t M1 = 1u << 20;
    float* Qraw = ws;                          // [0, 4M) floats
    float* Kraw = ws + 4 * M1;                 // [4M, 6M) — dead after prep_k
    float* Vraw = ws + 6 * M1;                 // [6M, 8M) — dead after prep_v
    float* AO   = ws + 4 * M1;                 // [4M, 8M) overlays Kraw+Vraw
    unsigned short* WqH = (unsigned short*)(ws +  8 * M1);
    unsigned short* WqL = (unsigned short*)(ws +  8 * M1 + M1 / 2);
    unsigned short* WkH = (unsigned short*)(ws +  9 * M1);
    unsigned short* WkL = (unsigned short*)(ws +  9 * M1 + M1 / 4);
    unsigned short* WvH = (unsigned short*)(ws +  9 * M1 + M1 / 2);
    unsigned short* WvL = (unsigned short*)(ws +  9 * M1 + 3 * (M1 / 4));
    unsigned short* WoH = (unsigned short*)(ws + 10 * M1);
    unsigned short* WoL = (unsigned short*)(ws + 10 * M1 + M1 / 2);
    unsigned short* KH  = (unsigned short*)(ws + 11 * M1);
    unsigned short* KL  = (unsigned short*)(ws + 12 * M1);
    unsigned short* VT  = (unsigned short*)(ws + 13 * M1);
    float* out = (float*)d_out;

    static bool attr_set = false;
    if (!attr_set) {
        hipFuncSetAttribute((const void*)attn,
                            hipFuncAttributeMaxDynamicSharedMemorySize, 75520);
        attr_set = true;
    }

    dim3 blk(256);
    prep_wt<<<dim3(16, 16), blk, 0, stream>>>(wq, WqH, WqL, 1024, 1024);
    prep_wt<<<dim3(16,  8), blk, 0, stream>>>(wk, WkH, WkL, 1024, 512);
    prep_wt<<<dim3(16,  8), blk, 0, stream>>>(wv, WvH, WvL, 1024, 512);
    prep_wt<<<dim3(16, 16), blk, 0, stream>>>(wo, WoH, WoL, 1024, 1024);
    gemm_mfma<<<dim3(32, 8), blk, 0, stream>>>(hs, WqH, WqL, Qraw, 1024, 1024);
    gemm_mfma<<<dim3(32, 4), blk, 0, stream>>>(hs, WkH, WkL, Kraw, 1024, 512);
    gemm_mfma<<<dim3(32, 4), blk, 0, stream>>>(hs, WvH, WvL, Vraw, 1024, 512);
    rope_q<<<dim3(8192), blk, 0, stream>>>(Qraw, pos);
    prep_k<<<dim3(8192), blk, 0, stream>>>(Kraw, KH, KL, pos);
    prep_v<<<dim3(512),  blk, 0, stream>>>(Vraw, VT);
    attn<<<dim3(4096), dim3(1024), 75520, stream>>>(Qraw, KH, KL, VT, AO);
    gemm_mfma<<<dim3(32, 8), blk, 0, stream>>>(AO, WoH, WoL, out, 1024, 1024);
}

// Round 8
// 1097.919 us; speedup vs baseline: 1.0943x; 1.0943x over previous
//
#include <hip/hip_runtime.h>
#include <cstdint>
#include <cstddef>

typedef unsigned int u32;
typedef unsigned long long u64;
typedef __attribute__((ext_vector_type(8))) short s8v;   // 8 bf16 (4 VGPRs)
typedef __attribute__((ext_vector_type(4))) float f4v;   // MFMA C/D

#define B_   2
#define L_   2048
#define D_   1024
#define NH_  16
#define KVH_ 8
#define DH_  64
#define TOPK_ 1024

#define MFMA16(a, b, c) __builtin_amdgcn_mfma_f32_16x16x32_bf16(a, b, c, 0, 0, 0)

// order-preserving float->uint key (descending float == descending uint)
__device__ __forceinline__ u32 fkey(float s) {
    u32 b = __float_as_uint(s);
    return b ^ ((u32)((int)b >> 31) | 0x80000000u);
}
// exact inverse of fkey
__device__ __forceinline__ float fkeyinv(u32 k) {
    u32 b = (k & 0x80000000u) ? (k ^ 0x80000000u) : ~k;
    return __uint_as_float(b);
}
// fp32 -> bf16 round-to-nearest-even, as raw ushort
__device__ __forceinline__ unsigned short bf16rne(float x) {
    u32 u = __float_as_uint(x);
    u32 r = (u + 0x7FFFu + ((u >> 16) & 1u)) >> 16;
    return (unsigned short)r;
}
__device__ __forceinline__ float bf2f(unsigned short h) {
    return __uint_as_float((u32)h << 16);
}

// ---------------------------------------------------------------------------
// W [K][N] fp32 -> WtH/WtL [N][K] bf16 hi/lo (transpose + split). grid (K/64, N/64)
// ---------------------------------------------------------------------------
__global__ __launch_bounds__(256) void prep_wt(const float* __restrict__ W,
                                               unsigned short* __restrict__ WtH,
                                               unsigned short* __restrict__ WtL,
                                               int K, int N) {
    __shared__ float tile[64 * 65];
    int k0 = blockIdx.x * 64, n0 = blockIdx.y * 64;
    int t = threadIdx.x;
#pragma unroll
    for (int i = 0; i < 16; ++i) {
        int idx = t + i * 256;
        int kk = idx >> 6, nn = idx & 63;
        tile[kk * 65 + nn] = W[(size_t)(k0 + kk) * N + n0 + nn];
    }
    __syncthreads();
#pragma unroll
    for (int i = 0; i < 16; ++i) {
        int idx = t + i * 256;
        int nn = idx >> 6, kk = idx & 63;
        float x = tile[kk * 65 + nn];
        unsigned short hi = bf16rne(x);
        unsigned short lo = bf16rne(x - bf2f(hi));
        WtH[(size_t)(n0 + nn) * K + k0 + kk] = hi;
        WtL[(size_t)(n0 + nn) * K + k0 + kk] = lo;
    }
}

// ---------------------------------------------------------------------------
// MFMA GEMM: C[M][N] fp32 = A[M][K] fp32 @ Wt([N][K] bf16 hi/lo), 3-term hi/lo.
// BM=128, BN=128, BK=32; 256 threads (4 waves, 2x2 of 64x64). grid (M/128, N/128)
// XCD-chunked block swizzle (nwg%8==0 for all shapes).
// ---------------------------------------------------------------------------
__global__ __launch_bounds__(256) void gemm_mfma(
    const float* __restrict__ A,
    const unsigned short* __restrict__ Wh,
    const unsigned short* __restrict__ Wl,
    float* __restrict__ C, int K, int N) {
    __shared__ __align__(16) unsigned short lAh[128 * 40];
    __shared__ __align__(16) unsigned short lAl[128 * 40];
    __shared__ __align__(16) unsigned short lBh[128 * 40];
    __shared__ __align__(16) unsigned short lBl[128 * 40];
    const int t = threadIdx.x, lane = t & 63, w = t >> 6;
    const int quad = lane >> 4, col = lane & 15;
    const int wm = w >> 1, wn = w & 1;
    const int nwg = gridDim.x * gridDim.y;
    const int lin = blockIdx.y * gridDim.x + blockIdx.x;
    const int swz = (lin & 7) * (nwg >> 3) + (lin >> 3);
    const int bx = swz % gridDim.x, by = swz / gridDim.x;
    const int m0 = bx * 128, n0 = by * 128;
    const int sr = t >> 1, sk = (t & 1) * 16;

    f4v acc[4][4];
#pragma unroll
    for (int i = 0; i < 4; ++i)
#pragma unroll
        for (int j = 0; j < 4; ++j) acc[i][j] = (f4v){0.f, 0.f, 0.f, 0.f};

    for (int k0 = 0; k0 < K; k0 += 32) {
        const float* ap = A + (size_t)(m0 + sr) * K + k0 + sk;
        float4 a0 = *(const float4*)(ap);
        float4 a1 = *(const float4*)(ap + 4);
        float4 a2 = *(const float4*)(ap + 8);
        float4 a3 = *(const float4*)(ap + 12);
        s8v bh0 = *(const s8v*)(Wh + (size_t)(n0 + sr) * K + k0 + sk);
        s8v bh1 = *(const s8v*)(Wh + (size_t)(n0 + sr) * K + k0 + sk + 8);
        s8v bl0 = *(const s8v*)(Wl + (size_t)(n0 + sr) * K + k0 + sk);
        s8v bl1 = *(const s8v*)(Wl + (size_t)(n0 + sr) * K + k0 + sk + 8);
        float av[16] = {a0.x, a0.y, a0.z, a0.w, a1.x, a1.y, a1.z, a1.w,
                        a2.x, a2.y, a2.z, a2.w, a3.x, a3.y, a3.z, a3.w};
        union { s8v v; unsigned short u[8]; } ah_[2], al_[2];
#pragma unroll
        for (int i = 0; i < 16; ++i) {
            unsigned short hi = bf16rne(av[i]);
            ah_[i >> 3].u[i & 7] = hi;
            al_[i >> 3].u[i & 7] = bf16rne(av[i] - bf2f(hi));
        }
        __syncthreads();
        *(s8v*)&lAh[sr * 40 + sk]     = ah_[0].v;
        *(s8v*)&lAh[sr * 40 + sk + 8] = ah_[1].v;
        *(s8v*)&lAl[sr * 40 + sk]     = al_[0].v;
        *(s8v*)&lAl[sr * 40 + sk + 8] = al_[1].v;
        *(s8v*)&lBh[sr * 40 + sk]     = bh0;
        *(s8v*)&lBh[sr * 40 + sk + 8] = bh1;
        *(s8v*)&lBl[sr * 40 + sk]     = bl0;
        *(s8v*)&lBl[sr * 40 + sk + 8] = bl1;
        __syncthreads();
        s8v amh[4], aml[4], bnh[4], bnl[4];
#pragma unroll
        for (int mt = 0; mt < 4; ++mt) {
            amh[mt] = *(s8v*)&lAh[(wm * 64 + mt * 16 + col) * 40 + quad * 8];
            aml[mt] = *(s8v*)&lAl[(wm * 64 + mt * 16 + col) * 40 + quad * 8];
        }
#pragma unroll
        for (int nt = 0; nt < 4; ++nt) {
            bnh[nt] = *(s8v*)&lBh[(wn * 64 + nt * 16 + col) * 40 + quad * 8];
            bnl[nt] = *(s8v*)&lBl[(wn * 64 + nt * 16 + col) * 40 + quad * 8];
        }
#pragma unroll
        for (int mt = 0; mt < 4; ++mt)
#pragma unroll
            for (int nt = 0; nt < 4; ++nt) {
                acc[mt][nt] = MFMA16(amh[mt], bnh[nt], acc[mt][nt]);
                acc[mt][nt] = MFMA16(amh[mt], bnl[nt], acc[mt][nt]);
                acc[mt][nt] = MFMA16(aml[mt], bnh[nt], acc[mt][nt]);
            }
    }
#pragma unroll
    for (int mt = 0; mt < 4; ++mt)
#pragma unroll
        for (int nt = 0; nt < 4; ++nt)
#pragma unroll
            for (int r = 0; r < 4; ++r)
                C[(size_t)(m0 + wm * 64 + mt * 16 + quad * 4 + r) * N +
                  n0 + wn * 64 + nt * 16 + col] = acc[mt][nt][r];
}

// ---------------------------------------------------------------------------
// RoPE on Q, in place. Layout [b][l][h][d].
// ---------------------------------------------------------------------------
__global__ __launch_bounds__(256) void rope_q(float* __restrict__ Q,
                                              const int* __restrict__ pos) {
    int tid = blockIdx.x * 256 + threadIdx.x;
    int dl = tid & 31;
    int h  = (tid >> 5) & 15;
    int l  = (tid >> 9) & 2047;
    int b  = tid >> 20;
    size_t base = ((size_t)(b * L_ + l) * NH_ + h) * DH_;
    float x1 = Q[base + dl];
    float x2 = Q[base + dl + 32];
    float p = (float)pos[b * L_ + l];
    float invf = (float)pow(10000.0, -(double)dl / 32.0);
    float a = p * invf;
    float s, c;
    sincosf(a, &s, &c);
    Q[base + dl]      = x1 * c - x2 * s;
    Q[base + dl + 32] = x2 * c + x1 * s;
}

// ---------------------------------------------------------------------------
// RoPE on K + hi/lo bf16 split. Input: fused KV gemm output, row stride 1024,
// K at cols [kvh*64 .. kvh*64+63]. Output layout [b][kvh][l][d].
// ---------------------------------------------------------------------------
__global__ __launch_bounds__(256) void prep_k(const float* __restrict__ KVraw,
                                              unsigned short* __restrict__ KHp,
                                              unsigned short* __restrict__ KLp,
                                              const int* __restrict__ pos) {
    int tid = blockIdx.x * 256 + threadIdx.x;
    int d   = tid & 63;
    int l   = (tid >> 6) & 2047;
    int kvh = (tid >> 17) & 7;
    int b   = tid >> 20;
    size_t src = (size_t)(b * L_ + l) * 1024 + kvh * DH_;
    float x  = KVraw[src + d];
    int dp   = (d < 32) ? d + 32 : d - 32;
    float xp = KVraw[src + dp];
    float p = (float)pos[b * L_ + l];
    int i = d & 31;
    float invf = (float)pow(10000.0, -(double)i / 32.0);
    float a = p * invf;
    float s, c;
    sincosf(a, &s, &c);
    float out = (d < 32) ? (x * c - xp * s) : (x * c + xp * s);
    unsigned short hi = bf16rne(out);
    unsigned short lo = bf16rne(out - bf2f(hi));
    size_t dst = ((size_t)(b * KVH_ + kvh) * L_ + l) * DH_ + d;
    KHp[dst] = hi;
    KLp[dst] = lo;
}

// ---------------------------------------------------------------------------
// V transpose to bf16 from fused KV gemm output (V at col 512 + kvh*64 + d,
// row stride 1024) -> VT[b][kvh][d][l]
// ---------------------------------------------------------------------------
__global__ __launch_bounds__(256) void prep_v(const float* __restrict__ KVraw,
                                              unsigned short* __restrict__ VTp) {
    __shared__ float tile[64 * 65];
    int bid = blockIdx.x;
    int lb  = bid & 31;
    int kvh = (bid >> 5) & 7;
    int b   = bid >> 8;
    int l0  = lb * 64;
    int t   = threadIdx.x;
#pragma unroll
    for (int i = 0; i < 16; ++i) {
        int idx = t + i * 256;
        int ll = idx >> 6, d = idx & 63;
        tile[ll * 65 + d] =
            KVraw[(size_t)(b * L_ + l0 + ll) * 1024 + 512 + kvh * DH_ + d];
    }
    __syncthreads();
#pragma unroll
    for (int i = 0; i < 16; ++i) {
        int idx = t + i * 256;
        int d = idx >> 6, ll = idx & 63;
        VTp[((size_t)(b * KVH_ + kvh) * DH_ + d) * L_ + l0 + ll] = bf16rne(tile[ll * 65 + d]);
    }
}

// ---------------------------------------------------------------------------
// Fused sparse attention, R16: consolidation after the R13/R15 occupancy
// dead-end (score state 128KB/block is fundamental: 1 block/CU in regs OR
// LDS, never 2). Ledger: only work/serial-chain cuts moved time (R9/R11/R14).
// This round: (a) single Sc buffer for BOTH J-passes (LDS is free at 1
// block/CU): produce all 8 tj as one ILP region, ONE barrier, read all 32
// keys -> removes 2 barriers + the jp0-read->jp1-produce serialization.
// Sc stride 2050 floats: quad write offset 4*2050%32=8 banks -> conflict-free.
// (b) restore kc0 V-prefetch; (c) no launch-bounds cap (no spills; falsifier
// for spills is WRITE_SIZE >> 16MB).
// ---------------------------------------------------------------------------
__global__ __launch_bounds__(1024) void attn(
    const float* __restrict__ QR,
    const unsigned short* __restrict__ KH,
    const unsigned short* __restrict__ KL,
    const unsigned short* __restrict__ VT,
    float* __restrict__ AO) {

    extern __shared__ __align__(16) unsigned char dynsm[];
    float* Sc = (float*)dynsm;                               // [16*2050] 131200B
    unsigned short* Pc = (unsigned short*)dynsm;             // [16*2072] 66304B (union)
    u32* hist = (u32*)dynsm;                                 // [16*1024] 65536B (union)
    float* qtile  = (float*)(dynsm + 131200);                // [16*68] 4352B
    float* outred = (float*)(dynsm + 131200 + 4352);         // [16*68] 4352B

    const int t = threadIdx.x;
    const int lane = t & 63, w = t >> 6;            // w in [0,16)
    const int quad = lane >> 4, col = lane & 15;
    // XCD-chunked remap (bijective: 4096 % 8 == 0)
    const int bid0 = blockIdx.x;
    const int bid  = (bid0 & 7) * 512 + (bid0 >> 3);
    const int l0  = (bid & 255) * 8;
    const int kvh = (bid >> 8) & 7;
    const int b   = bid >> 11;

    // ---- load Q tile (16 rows = 8 l-pos x heads {2kvh, 2kvh+1}); zero outred
    if (t < 256) {
        int q = t >> 4, d4 = (t & 15) * 4;
        *(float4*)&qtile[q * 68 + d4] =
            *(const float4*)(QR + ((size_t)((b * L_ + l0 + (q & 7)) * NH_ +
                                            kvh * 2 + (q >> 3))) * DH_ + d4);
    }
    outred[t] = 0.f;
    if (t < 64) outred[1024 + t] = 0.f;
    __syncthreads();

    // ---- build A-frags (hi/lo): A[m=col][k=ks*32+quad*8+i]; all 16 rows real
    union FR { s8v v; unsigned short u[8]; };
    FR ah[2], al[2];
#pragma unroll
    for (int ks = 0; ks < 2; ++ks)
#pragma unroll
        for (int i = 0; i < 8; ++i) {
            float x = qtile[col * 68 + ks * 32 + quad * 8 + i];
            unsigned short hi = bf16rne(x);
            ah[ks].u[i] = hi;
            al[ks].u[i] = bf16rne(x - bf2f(hi));
        }

    // ---- QK^T: all 2048 cols in one pass (wave slice = 128 cols, 8 tj),
    // single Sc buffer, one barrier, then transpose-read 32 keys.
    const size_t slabK = (size_t)(b * KVH_ + kvh) * L_ * DH_;
    const unsigned short* khp = KH + slabK;
    const unsigned short* klp = KL + slabK;
    u32 uk[32];   // row-w keys; elem i: j = 64*i + lane

#pragma unroll
    for (int tj = 0; tj < 8; ++tj) {
        int j0 = (tj >> 2) * 1024 + w * 64 + (tj & 3) * 16;
        const unsigned short* kh8 = khp + (size_t)(j0 + col) * 64 + quad * 8;
        const unsigned short* kl8 = klp + (size_t)(j0 + col) * 64 + quad * 8;
        s8v bh0 = *(const s8v*)(kh8);
        s8v bh1 = *(const s8v*)(kh8 + 32);
        s8v bl0 = *(const s8v*)(kl8);
        s8v bl1 = *(const s8v*)(kl8 + 32);
        f4v c = {0.f, 0.f, 0.f, 0.f};
        c = MFMA16(ah[0].v, bh0, c);
        c = MFMA16(al[0].v, bh0, c);
        c = MFMA16(ah[0].v, bl0, c);
        c = MFMA16(ah[1].v, bh1, c);
        c = MFMA16(al[1].v, bh1, c);
        c = MFMA16(ah[1].v, bl1, c);
        c = c * 0.125f;                  // DH^-0.5
#pragma unroll
        for (int r = 0; r < 4; ++r)
            Sc[(quad * 4 + r) * 2050 + j0 + col] = c[r];
    }
    __syncthreads();                     // all Sc written
#pragma unroll
    for (int i = 0; i < 32; ++i)
        uk[i] = fkey(Sc[w * 2050 + i * 64 + lane]);
    __syncthreads();                     // Sc reads done; hist region free

    // ---- order-preserving key normalization: spread radix digits.
    u32 ulo = 0xFFFFFFFFu, uhi = 0u;
#pragma unroll
    for (int i = 0; i < 32; ++i) {
        u32 u = uk[i];
        ulo = (u < ulo) ? u : ulo;
        uhi = (u > uhi) ? u : uhi;
    }
    for (int off = 1; off < 64; off <<= 1) {
        u32 ol = (u32)__shfl_xor((int)ulo, off);
        u32 oh = (u32)__shfl_xor((int)uhi, off);
        ulo = (ol < ulo) ? ol : ulo;
        uhi = (oh > uhi) ? oh : uhi;
    }
    const float mrow = fkeyinv(uhi);     // row max, free from the reduction
    const int sh = __clz((int)((uhi - ulo) | 1u));   // 0..31
#pragma unroll
    for (int i = 0; i < 32; ++i) uk[i] = (uk[i] - ulo) << sh;

    // ---- wave-local exact top-1024: radix with wave-uniform early-exit.
    // Digit d, replica lane&3 at hq[(d&3)*256 + (d>>2)*4 + (lane&3)].
    u32 pf = 0u, kq = (u32)TOPK_, ng = 0u, geq = 0u;
    u32* hq = &hist[w * 1024];
    const int rep = lane & 3;
    for (int pass = 0; pass < 4; ++pass) {
        int shift = 24 - 8 * pass;
#pragma unroll
        for (int i = 0; i < 4; ++i)
            *(uint4*)&hq[i * 256 + lane * 4] = make_uint4(0u, 0u, 0u, 0u);
        u32 pm = pass ? (0xFFFFFFFFu << (shift + 8)) : 0u;
#pragma unroll
        for (int i = 0; i < 32; ++i) {
            u32 u = uk[i];
            if ((u & pm) == pf) {
                u32 d = (u >> shift) & 255u;
                atomicAdd(&hq[(d & 3) * 256 + (d >> 2) * 4 + rep], 1u);
            }
        }
        // reads may-alias the atomics => real ds ops, wave-ordered.
        u32 hb_[4];
        u32 s4 = 0u;
#pragma unroll
        for (int bb = 0; bb < 4; ++bb) {
            uint4 hv = *(const uint4*)&hq[bb * 256 + lane * 4];
            hb_[bb] = hv.x + hv.y + hv.z + hv.w;
            s4 += hb_[bb];
        }
        u32 v = s4;
        for (int off = 1; off < 64; off <<= 1) {
            u32 tmp = __shfl_down(v, off);
            if (lane + off < 64) v += tmp;
        }
        u32 g = v - s4;                  // # keys with digit > 4*lane+3
        u32 mydig = 0u, myk = 0u, myng = 0u, myhb = 0u;
        bool found = false;
#pragma unroll
        for (int bb = 3; bb >= 0; --bb) {
            u32 hb = hb_[bb];
            if (hb && g < kq && kq <= g + hb) {   // true for exactly one (lane,bb)
                found = true;
                mydig = (u32)(4 * lane + bb);
                myk   = kq - g;
                myng  = ng + g;
                myhb  = hb;
            }
            g += hb;
        }
        u64 fm = __ballot(found);
        int src = (int)__builtin_ctzll(fm);
        pf |= ((u32)__shfl((int)mydig, src)) << shift;
        kq  = (u32)__shfl((int)myk,  src);
        ng  = (u32)__shfl((int)myng, src);
        u32 hbs = (u32)__shfl((int)myhb, src);
        if (kq == hbs) { geq = 1u; break; }  // whole bucket selected: exact
    }

    // ---- selection mask (wave-local, register state)
    const u32 uth = pf;
    u32 selm = 0u;
    if (geq) {
#pragma unroll
        for (int i = 0; i < 32; ++i)
            if (uk[i] >= uth) selm |= 1u << i;
    } else {
        const u32 quota = (u32)TOPK_ - ng;
        u32 eqm = 0u;
#pragma unroll
        for (int i = 0; i < 32; ++i) {
            u32 u = uk[i];
            if (u > uth) selm |= 1u << i;
            else if (u == uth) eqm |= 1u << i;
        }
        u32 ec = (u32)__builtin_popcount(eqm);
        for (int off = 1; off < 64; off <<= 1) ec += __shfl_xor(ec, off);
        if (ec == quota) {
            selm |= eqm;                 // common case: take all tied entries
        } else {                         // rare: rank ties by lowest index j
            u32 base = 0;
            u64 lmask = ((u64)1 << lane) - 1;
#pragma unroll
            for (int i = 0; i < 32; ++i) {
                u64 mm = __ballot((eqm >> i) & 1u);
                if ((eqm >> i) & 1u) {
                    u32 rk = base + (u32)__builtin_popcountll(mm & lmask);
                    if (rk < quota) selm |= 1u << i;
                }
                base += (u32)__builtin_popcountll(mm);
            }
        }
    }

    // ---- wave-local softmax (mrow from the min/max reduction), invZ in P
    float z = 0.f;
#pragma unroll
    for (int i = 0; i < 32; ++i) {
        float vv = fkeyinv((uk[i] >> sh) + ulo);          // exact inverse
        float e = ((selm >> i) & 1u) ? __expf(vv - mrow) : 0.f;
        uk[i] = __float_as_uint(e);      // keys dead; reuse as e-storage
        z += e;
    }
    for (int off = 1; off < 64; off <<= 1) z += __shfl_xor(z, off);
    float invZ = 1.0f / z;

    // ---- prefetch kc0 V tiles (L2 loads overlap the P barriers)
    const unsigned short* vt = VT + (size_t)(b * KVH_ + kvh) * DH_ * L_;
    const int jb0 = w * 128 + quad * 8;
    s8v pv0 = *(const s8v*)(vt + (size_t)( 0 + col) * L_ + jb0);
    s8v pv1 = *(const s8v*)(vt + (size_t)(16 + col) * L_ + jb0);
    s8v pv2 = *(const s8v*)(vt + (size_t)(32 + col) * L_ + jb0);
    s8v pv3 = *(const s8v*)(vt + (size_t)(48 + col) * L_ + jb0);

    // ---- P -> Pc (bf16, invZ folded); row w  (Pc[w][j], j = 64*(i&15)+lane
    // + 1024*(i>>4))
    __syncthreads();                     // hist use done; Pc region free
#pragma unroll
    for (int i = 0; i < 32; ++i) {
        unsigned short pv16 = bf16rne(__uint_as_float(uk[i]) * invZ);
        Pc[w * 2072 + 1024 * (i >> 4) + 64 * (i & 15) + lane] = pv16;
    }
    __syncthreads();                     // all P rows written

    // ---- PV via MFMA; wave w covers j in [128w, 128w+128) in 4 sub-chunks
    f4v acc0 = {0.f, 0.f, 0.f, 0.f}, acc1 = acc0, acc2 = acc0, acc3 = acc0;
    {
        s8v ap = *(const s8v*)&Pc[col * 2072 + jb0];
        acc0 = MFMA16(ap, pv0, acc0);
        acc1 = MFMA16(ap, pv1, acc1);
        acc2 = MFMA16(ap, pv2, acc2);
        acc3 = MFMA16(ap, pv3, acc3);
    }
#pragma unroll
    for (int kc = 1; kc < 4; ++kc) {
        int jb = w * 128 + kc * 32 + quad * 8;
        s8v ap = *(const s8v*)&Pc[col * 2072 + jb];
        s8v v0 = *(const s8v*)(vt + (size_t)( 0 + col) * L_ + jb);
        s8v v1 = *(const s8v*)(vt + (size_t)(16 + col) * L_ + jb);
        s8v v2 = *(const s8v*)(vt + (size_t)(32 + col) * L_ + jb);
        s8v v3 = *(const s8v*)(vt + (size_t)(48 + col) * L_ + jb);
        acc0 = MFMA16(ap, v0, acc0);
        acc1 = MFMA16(ap, v1, acc1);
        acc2 = MFMA16(ap, v2, acc2);
        acc3 = MFMA16(ap, v3, acc3);
    }

    // ---- cross-wave PV reduction (all 16 rows live) + store
#pragma unroll
    for (int r = 0; r < 4; ++r) {
        atomicAdd(&outred[(quad * 4 + r) * 68 +  0 + col], acc0[r]);
        atomicAdd(&outred[(quad * 4 + r) * 68 + 16 + col], acc1[r]);
        atomicAdd(&outred[(quad * 4 + r) * 68 + 32 + col], acc2[r]);
        atomicAdd(&outred[(quad * 4 + r) * 68 + 48 + col], acc3[r]);
    }
    __syncthreads();
    if (t < 256) {
        int q = t >> 4, d4 = (t & 15) * 4;
        float4 o = *(float4*)&outred[q * 68 + d4];
        *(float4*)(AO + ((size_t)((b * L_ + l0 + (q & 7)) * NH_ +
                                  kvh * 2 + (q >> 3))) * DH_ + d4) = o;
    }
}

// ---------------------------------------------------------------------------
extern "C" void kernel_launch(void* const* d_in, const int* in_sizes, int n_in,
                              void* d_out, int out_size, void* d_ws, size_t ws_size,
                              hipStream_t stream) {
    const float* hs = (const float*)d_in[0];
    const float* wq = (const float*)d_in[1];
    const float* wk = (const float*)d_in[2];
    const float* wv = (const float*)d_in[3];
    const float* wo = (const float*)d_in[4];
    const int*  pos = (const int*)d_in[5];

    float* ws = (float*)d_ws;
    const size_t M1 = 1u << 20;
    float* Qraw  = ws;                         // [0, 4M) floats
    float* KVraw = ws + 4 * M1;                // [4M, 8M) fused K|V, stride 1024
    float* AO    = ws + 4 * M1;                // overlays KVraw (dead after preps)
    unsigned short* WqH = (unsigned short*)(ws +  8 * M1);
    unsigned short* WqL = (unsigned short*)(ws +  8 * M1 + M1 / 2);
    unsigned short* KVh = (unsigned short*)(ws +  9 * M1);          // [1024][1024]
    unsigned short* KVl = (unsigned short*)(ws +  9 * M1 + M1 / 2);
    unsigned short* WoH = (unsigned short*)(ws + 10 * M1);
    unsigned short* WoL = (unsigned short*)(ws + 10 * M1 + M1 / 2);
    unsigned short* KH  = (unsigned short*)(ws + 11 * M1);
    unsigned short* KL  = (unsigned short*)(ws + 12 * M1);
    unsigned short* VT  = (unsigned short*)(ws + 13 * M1);
    float* out = (float*)d_out;

    static bool attr_set = false;
    if (!attr_set) {
        hipFuncSetAttribute((const void*)attn,
                            hipFuncAttributeMaxDynamicSharedMemorySize, 139904);
        attr_set = true;
    }

    dim3 blk(256);
    prep_wt<<<dim3(16, 16), blk, 0, stream>>>(wq, WqH, WqL, 1024, 1024);
    // fused K|V weights: Wk -> rows 0..511, Wv -> rows 512..1023 of [1024][1024]
    prep_wt<<<dim3(16,  8), blk, 0, stream>>>(wk, KVh, KVl, 1024, 512);
    prep_wt<<<dim3(16,  8), blk, 0, stream>>>(wv, KVh + (size_t)512 * 1024,
                                              KVl + (size_t)512 * 1024, 1024, 512);
    prep_wt<<<dim3(16, 16), blk, 0, stream>>>(wo, WoH, WoL, 1024, 1024);
    gemm_mfma<<<dim3(32, 8), blk, 0, stream>>>(hs, WqH, WqL, Qraw, 1024, 1024);
    // fused K+V projection: full-GPU grid instead of 2 half-idle launches
    gemm_mfma<<<dim3(32, 8), blk, 0, stream>>>(hs, KVh, KVl, KVraw, 1024, 1024);
    rope_q<<<dim3(8192), blk, 0, stream>>>(Qraw, pos);
    prep_k<<<dim3(8192), blk, 0, stream>>>(KVraw, KH, KL, pos);
    prep_v<<<dim3(512),  blk, 0, stream>>>(KVraw, VT);
    attn<<<dim3(4096), dim3(1024), 139904, stream>>>(Qraw, KH, KL, VT, AO);
    gemm_mfma<<<dim3(32, 8), blk, 0, stream>>>(AO, WoH, WoL, out, 1024, 1024);
}

// Round 9
// 1040.887 us; speedup vs baseline: 1.1543x; 1.0548x over previous
//
#include <hip/hip_runtime.h>
#include <cstdint>
#include <cstddef>

typedef unsigned int u32;
typedef unsigned long long u64;
typedef __attribute__((ext_vector_type(8))) short s8v;   // 8 bf16 (4 VGPRs)
typedef __attribute__((ext_vector_type(4))) float f4v;   // MFMA C/D
typedef __attribute__((ext_vector_type(4))) unsigned short us4;

#define B_   2
#define L_   2048
#define D_   1024
#define NH_  16
#define KVH_ 8
#define DH_  64
#define TOPK_ 1024

#define MFMA16(a, b, c) __builtin_amdgcn_mfma_f32_16x16x32_bf16(a, b, c, 0, 0, 0)

// order-preserving float->uint key (descending float == descending uint)
__device__ __forceinline__ u32 fkey(float s) {
    u32 b = __float_as_uint(s);
    return b ^ ((u32)((int)b >> 31) | 0x80000000u);
}
// exact inverse of fkey
__device__ __forceinline__ float fkeyinv(u32 k) {
    u32 b = (k & 0x80000000u) ? (k ^ 0x80000000u) : ~k;
    return __uint_as_float(b);
}
// fp32 -> bf16 round-to-nearest-even, as raw ushort
__device__ __forceinline__ unsigned short bf16rne(float x) {
    u32 u = __float_as_uint(x);
    u32 r = (u + 0x7FFFu + ((u >> 16) & 1u)) >> 16;
    return (unsigned short)r;
}
__device__ __forceinline__ float bf2f(unsigned short h) {
    return __uint_as_float((u32)h << 16);
}

// ---------------------------------------------------------------------------
// W [K][N] fp32 -> WtH/WtL [N][K] bf16 hi/lo (transpose + split). grid (K/64, N/64)
// ---------------------------------------------------------------------------
__global__ __launch_bounds__(256) void prep_wt(const float* __restrict__ W,
                                               unsigned short* __restrict__ WtH,
                                               unsigned short* __restrict__ WtL,
                                               int K, int N) {
    __shared__ float tile[64 * 65];
    int k0 = blockIdx.x * 64, n0 = blockIdx.y * 64;
    int t = threadIdx.x;
#pragma unroll
    for (int i = 0; i < 16; ++i) {
        int idx = t + i * 256;
        int kk = idx >> 6, nn = idx & 63;
        tile[kk * 65 + nn] = W[(size_t)(k0 + kk) * N + n0 + nn];
    }
    __syncthreads();
#pragma unroll
    for (int i = 0; i < 16; ++i) {
        int idx = t + i * 256;
        int nn = idx >> 6, kk = idx & 63;
        float x = tile[kk * 65 + nn];
        unsigned short hi = bf16rne(x);
        unsigned short lo = bf16rne(x - bf2f(hi));
        WtH[(size_t)(n0 + nn) * K + k0 + kk] = hi;
        WtL[(size_t)(n0 + nn) * K + k0 + kk] = lo;
    }
}

// ---------------------------------------------------------------------------
// A [M][K] fp32 -> AH/AL bf16 hi/lo (same layout). 4 elems/thread.
// ---------------------------------------------------------------------------
__global__ __launch_bounds__(256) void split_a(const float* __restrict__ A,
                                               unsigned short* __restrict__ AH,
                                               unsigned short* __restrict__ AL) {
    size_t tid = (size_t)blockIdx.x * 256 + threadIdx.x;
    float4 v = *(const float4*)(A + tid * 4);
    us4 hv, lv;
    float x[4] = {v.x, v.y, v.z, v.w};
#pragma unroll
    for (int i = 0; i < 4; ++i) {
        unsigned short hi = bf16rne(x[i]);
        hv[i] = hi;
        lv[i] = bf16rne(x[i] - bf2f(hi));
    }
    *(us4*)(AH + tid * 4) = hv;
    *(us4*)(AL + tid * 4) = lv;
}

// ---------------------------------------------------------------------------
// MFMA GEMM, bf16-A variant: C[M][N] fp32 = A(hi/lo bf16, row stride lda)
// @ Wt([N][K] bf16 hi/lo), 3-term hi/lo. BM=BN=128, BK=32; 256 thr.
// grid (M/128, N/128), XCD-chunked swizzle (nwg%8==0).
// Pre-split A removes the per-tile fp32->bf16 convert (48 VALU/thread/k-iter,
// redundant across N/128 block-columns) and halves A fetch.
// ---------------------------------------------------------------------------
__global__ __launch_bounds__(256) void gemm_bf(
    const unsigned short* __restrict__ Ah,
    const unsigned short* __restrict__ Al,
    int lda,
    const unsigned short* __restrict__ Wh,
    const unsigned short* __restrict__ Wl,
    float* __restrict__ C, int K, int N) {
    __shared__ __align__(16) unsigned short lAh[128 * 40];
    __shared__ __align__(16) unsigned short lAl[128 * 40];
    __shared__ __align__(16) unsigned short lBh[128 * 40];
    __shared__ __align__(16) unsigned short lBl[128 * 40];
    const int t = threadIdx.x, lane = t & 63, w = t >> 6;
    const int quad = lane >> 4, col = lane & 15;
    const int wm = w >> 1, wn = w & 1;
    const int nwg = gridDim.x * gridDim.y;
    const int lin = blockIdx.y * gridDim.x + blockIdx.x;
    const int swz = (lin & 7) * (nwg >> 3) + (lin >> 3);
    const int bx = swz % gridDim.x, by = swz / gridDim.x;
    const int m0 = bx * 128, n0 = by * 128;
    const int sr = t >> 1, sk = (t & 1) * 16;

    f4v acc[4][4];
#pragma unroll
    for (int i = 0; i < 4; ++i)
#pragma unroll
        for (int j = 0; j < 4; ++j) acc[i][j] = (f4v){0.f, 0.f, 0.f, 0.f};

    for (int k0 = 0; k0 < K; k0 += 32) {
        const unsigned short* ap = Ah + (size_t)(m0 + sr) * lda + k0 + sk;
        const unsigned short* alp = Al + (size_t)(m0 + sr) * lda + k0 + sk;
        s8v a_h0 = *(const s8v*)(ap);
        s8v a_h1 = *(const s8v*)(ap + 8);
        s8v a_l0 = *(const s8v*)(alp);
        s8v a_l1 = *(const s8v*)(alp + 8);
        s8v bh0 = *(const s8v*)(Wh + (size_t)(n0 + sr) * K + k0 + sk);
        s8v bh1 = *(const s8v*)(Wh + (size_t)(n0 + sr) * K + k0 + sk + 8);
        s8v bl0 = *(const s8v*)(Wl + (size_t)(n0 + sr) * K + k0 + sk);
        s8v bl1 = *(const s8v*)(Wl + (size_t)(n0 + sr) * K + k0 + sk + 8);
        __syncthreads();
        *(s8v*)&lAh[sr * 40 + sk]     = a_h0;
        *(s8v*)&lAh[sr * 40 + sk + 8] = a_h1;
        *(s8v*)&lAl[sr * 40 + sk]     = a_l0;
        *(s8v*)&lAl[sr * 40 + sk + 8] = a_l1;
        *(s8v*)&lBh[sr * 40 + sk]     = bh0;
        *(s8v*)&lBh[sr * 40 + sk + 8] = bh1;
        *(s8v*)&lBl[sr * 40 + sk]     = bl0;
        *(s8v*)&lBl[sr * 40 + sk + 8] = bl1;
        __syncthreads();
        s8v amh[4], aml[4], bnh[4], bnl[4];
#pragma unroll
        for (int mt = 0; mt < 4; ++mt) {
            amh[mt] = *(s8v*)&lAh[(wm * 64 + mt * 16 + col) * 40 + quad * 8];
            aml[mt] = *(s8v*)&lAl[(wm * 64 + mt * 16 + col) * 40 + quad * 8];
        }
#pragma unroll
        for (int nt = 0; nt < 4; ++nt) {
            bnh[nt] = *(s8v*)&lBh[(wn * 64 + nt * 16 + col) * 40 + quad * 8];
            bnl[nt] = *(s8v*)&lBl[(wn * 64 + nt * 16 + col) * 40 + quad * 8];
        }
#pragma unroll
        for (int mt = 0; mt < 4; ++mt)
#pragma unroll
            for (int nt = 0; nt < 4; ++nt) {
                acc[mt][nt] = MFMA16(amh[mt], bnh[nt], acc[mt][nt]);
                acc[mt][nt] = MFMA16(amh[mt], bnl[nt], acc[mt][nt]);
                acc[mt][nt] = MFMA16(aml[mt], bnh[nt], acc[mt][nt]);
            }
    }
#pragma unroll
    for (int mt = 0; mt < 4; ++mt)
#pragma unroll
        for (int nt = 0; nt < 4; ++nt)
#pragma unroll
            for (int r = 0; r < 4; ++r)
                C[(size_t)(m0 + wm * 64 + mt * 16 + quad * 4 + r) * N +
                  n0 + wn * 64 + nt * 16 + col] = acc[mt][nt][r];
}

// ---------------------------------------------------------------------------
// RoPE on Q, in place. Q in fused QKV buffer: row stride 2048, cols 0..1023.
// ---------------------------------------------------------------------------
__global__ __launch_bounds__(256) void rope_q(float* __restrict__ Q,
                                              const int* __restrict__ pos) {
    int tid = blockIdx.x * 256 + threadIdx.x;
    int dl = tid & 31;
    int h  = (tid >> 5) & 15;
    int l  = (tid >> 9) & 2047;
    int b  = tid >> 20;
    size_t base = (size_t)(b * L_ + l) * 2048 + h * DH_;
    float x1 = Q[base + dl];
    float x2 = Q[base + dl + 32];
    float p = (float)pos[b * L_ + l];
    float invf = (float)pow(10000.0, -(double)dl / 32.0);
    float a = p * invf;
    float s, c;
    sincosf(a, &s, &c);
    Q[base + dl]      = x1 * c - x2 * s;
    Q[base + dl + 32] = x2 * c + x1 * s;
}

// ---------------------------------------------------------------------------
// RoPE on K + hi/lo bf16 split. K in fused QKV: row stride 2048, col
// 1024 + kvh*64 + d. Output layout [b][kvh][l][d].
// ---------------------------------------------------------------------------
__global__ __launch_bounds__(256) void prep_k(const float* __restrict__ QKV,
                                              unsigned short* __restrict__ KHp,
                                              unsigned short* __restrict__ KLp,
                                              const int* __restrict__ pos) {
    int tid = blockIdx.x * 256 + threadIdx.x;
    int d   = tid & 63;
    int l   = (tid >> 6) & 2047;
    int kvh = (tid >> 17) & 7;
    int b   = tid >> 20;
    size_t src = (size_t)(b * L_ + l) * 2048 + 1024 + kvh * DH_;
    float x  = QKV[src + d];
    int dp   = (d < 32) ? d + 32 : d - 32;
    float xp = QKV[src + dp];
    float p = (float)pos[b * L_ + l];
    int i = d & 31;
    float invf = (float)pow(10000.0, -(double)i / 32.0);
    float a = p * invf;
    float s, c;
    sincosf(a, &s, &c);
    float out = (d < 32) ? (x * c - xp * s) : (x * c + xp * s);
    unsigned short hi = bf16rne(out);
    unsigned short lo = bf16rne(out - bf2f(hi));
    size_t dst = ((size_t)(b * KVH_ + kvh) * L_ + l) * DH_ + d;
    KHp[dst] = hi;
    KLp[dst] = lo;
}

// ---------------------------------------------------------------------------
// V transpose to bf16 from fused QKV (V at col 1536 + kvh*64 + d, stride 2048)
// -> VT[b][kvh][d][l]
// ---------------------------------------------------------------------------
__global__ __launch_bounds__(256) void prep_v(const float* __restrict__ QKV,
                                              unsigned short* __restrict__ VTp) {
    __shared__ float tile[64 * 65];
    int bid = blockIdx.x;
    int lb  = bid & 31;
    int kvh = (bid >> 5) & 7;
    int b   = bid >> 8;
    int l0  = lb * 64;
    int t   = threadIdx.x;
#pragma unroll
    for (int i = 0; i < 16; ++i) {
        int idx = t + i * 256;
        int ll = idx >> 6, d = idx & 63;
        tile[ll * 65 + d] =
            QKV[(size_t)(b * L_ + l0 + ll) * 2048 + 1536 + kvh * DH_ + d];
    }
    __syncthreads();
#pragma unroll
    for (int i = 0; i < 16; ++i) {
        int idx = t + i * 256;
        int d = idx >> 6, ll = idx & 63;
        VTp[((size_t)(b * KVH_ + kvh) * DH_ + d) * L_ + l0 + ll] = bf16rne(tile[ll * 65 + d]);
    }
}

// ---------------------------------------------------------------------------
// Fused sparse attention, R17 = R16 structure with (a) Q read from fused QKV
// (stride 2048) and (b) output written as bf16 hi/lo into the DEAD K/V
// columns of QKV (cols 1024..2047; K/V already extracted to KH/KL/VT) so the
// final GEMM reads pre-split A directly. Radix/softmax math untouched.
// ---------------------------------------------------------------------------
__global__ __launch_bounds__(1024) void attn(
    const float* __restrict__ QR,
    const unsigned short* __restrict__ KH,
    const unsigned short* __restrict__ KL,
    const unsigned short* __restrict__ VT,
    unsigned short* __restrict__ AOus) {

    extern __shared__ __align__(16) unsigned char dynsm[];
    float* Sc = (float*)dynsm;                               // [16*2050] 131200B
    unsigned short* Pc = (unsigned short*)dynsm;             // [16*2072] (union)
    u32* hist = (u32*)dynsm;                                 // [16*1024] (union)
    float* qtile  = (float*)(dynsm + 131200);                // [16*68] 4352B
    float* outred = (float*)(dynsm + 131200 + 4352);         // [16*68] 4352B

    const int t = threadIdx.x;
    const int lane = t & 63, w = t >> 6;            // w in [0,16)
    const int quad = lane >> 4, col = lane & 15;
    // XCD-chunked remap (bijective: 4096 % 8 == 0)
    const int bid0 = blockIdx.x;
    const int bid  = (bid0 & 7) * 512 + (bid0 >> 3);
    const int l0  = (bid & 255) * 8;
    const int kvh = (bid >> 8) & 7;
    const int b   = bid >> 11;

    // ---- load Q tile (16 rows = 8 l-pos x heads {2kvh, 2kvh+1}); zero outred
    if (t < 256) {
        int q = t >> 4, d4 = (t & 15) * 4;
        *(float4*)&qtile[q * 68 + d4] =
            *(const float4*)(QR + (size_t)(b * L_ + l0 + (q & 7)) * 2048 +
                             (kvh * 2 + (q >> 3)) * DH_ + d4);
    }
    outred[t] = 0.f;
    if (t < 64) outred[1024 + t] = 0.f;
    __syncthreads();

    // ---- build A-frags (hi/lo): A[m=col][k=ks*32+quad*8+i]; all 16 rows real
    union FR { s8v v; unsigned short u[8]; };
    FR ah[2], al[2];
#pragma unroll
    for (int ks = 0; ks < 2; ++ks)
#pragma unroll
        for (int i = 0; i < 8; ++i) {
            float x = qtile[col * 68 + ks * 32 + quad * 8 + i];
            unsigned short hi = bf16rne(x);
            ah[ks].u[i] = hi;
            al[ks].u[i] = bf16rne(x - bf2f(hi));
        }

    // ---- QK^T: all 2048 cols in one pass (wave slice = 128 cols, 8 tj),
    // single Sc buffer, one barrier, then transpose-read 32 keys.
    const size_t slabK = (size_t)(b * KVH_ + kvh) * L_ * DH_;
    const unsigned short* khp = KH + slabK;
    const unsigned short* klp = KL + slabK;
    u32 uk[32];   // row-w keys; elem i: j = 64*i + lane

#pragma unroll
    for (int tj = 0; tj < 8; ++tj) {
        int j0 = (tj >> 2) * 1024 + w * 64 + (tj & 3) * 16;
        const unsigned short* kh8 = khp + (size_t)(j0 + col) * 64 + quad * 8;
        const unsigned short* kl8 = klp + (size_t)(j0 + col) * 64 + quad * 8;
        s8v bh0 = *(const s8v*)(kh8);
        s8v bh1 = *(const s8v*)(kh8 + 32);
        s8v bl0 = *(const s8v*)(kl8);
        s8v bl1 = *(const s8v*)(kl8 + 32);
        f4v c = {0.f, 0.f, 0.f, 0.f};
        c = MFMA16(ah[0].v, bh0, c);
        c = MFMA16(al[0].v, bh0, c);
        c = MFMA16(ah[0].v, bl0, c);
        c = MFMA16(ah[1].v, bh1, c);
        c = MFMA16(al[1].v, bh1, c);
        c = MFMA16(ah[1].v, bl1, c);
        c = c * 0.125f;                  // DH^-0.5
#pragma unroll
        for (int r = 0; r < 4; ++r)
            Sc[(quad * 4 + r) * 2050 + j0 + col] = c[r];
    }
    __syncthreads();                     // all Sc written
#pragma unroll
    for (int i = 0; i < 32; ++i)
        uk[i] = fkey(Sc[w * 2050 + i * 64 + lane]);
    __syncthreads();                     // Sc reads done; hist region free

    // ---- order-preserving key normalization: spread radix digits.
    u32 ulo = 0xFFFFFFFFu, uhi = 0u;
#pragma unroll
    for (int i = 0; i < 32; ++i) {
        u32 u = uk[i];
        ulo = (u < ulo) ? u : ulo;
        uhi = (u > uhi) ? u : uhi;
    }
    for (int off = 1; off < 64; off <<= 1) {
        u32 ol = (u32)__shfl_xor((int)ulo, off);
        u32 oh = (u32)__shfl_xor((int)uhi, off);
        ulo = (ol < ulo) ? ol : ulo;
        uhi = (oh > uhi) ? oh : uhi;
    }
    const float mrow = fkeyinv(uhi);     // row max, free from the reduction
    const int sh = __clz((int)((uhi - ulo) | 1u));   // 0..31
#pragma unroll
    for (int i = 0; i < 32; ++i) uk[i] = (uk[i] - ulo) << sh;

    // ---- wave-local exact top-1024: radix with wave-uniform early-exit.
    // Digit d, replica lane&3 at hq[(d&3)*256 + (d>>2)*4 + (lane&3)].
    u32 pf = 0u, kq = (u32)TOPK_, ng = 0u, geq = 0u;
    u32* hq = &hist[w * 1024];
    const int rep = lane & 3;
    for (int pass = 0; pass < 4; ++pass) {
        int shift = 24 - 8 * pass;
#pragma unroll
        for (int i = 0; i < 4; ++i)
            *(uint4*)&hq[i * 256 + lane * 4] = make_uint4(0u, 0u, 0u, 0u);
        u32 pm = pass ? (0xFFFFFFFFu << (shift + 8)) : 0u;
#pragma unroll
        for (int i = 0; i < 32; ++i) {
            u32 u = uk[i];
            if ((u & pm) == pf) {
                u32 d = (u >> shift) & 255u;
                atomicAdd(&hq[(d & 3) * 256 + (d >> 2) * 4 + rep], 1u);
            }
        }
        // reads may-alias the atomics => real ds ops, wave-ordered.
        u32 hb_[4];
        u32 s4 = 0u;
#pragma unroll
        for (int bb = 0; bb < 4; ++bb) {
            uint4 hv = *(const uint4*)&hq[bb * 256 + lane * 4];
            hb_[bb] = hv.x + hv.y + hv.z + hv.w;
            s4 += hb_[bb];
        }
        u32 v = s4;
        for (int off = 1; off < 64; off <<= 1) {
            u32 tmp = __shfl_down(v, off);
            if (lane + off < 64) v += tmp;
        }
        u32 g = v - s4;                  // # keys with digit > 4*lane+3
        u32 mydig = 0u, myk = 0u, myng = 0u, myhb = 0u;
        bool found = false;
#pragma unroll
        for (int bb = 3; bb >= 0; --bb) {
            u32 hb = hb_[bb];
            if (hb && g < kq && kq <= g + hb) {   // true for exactly one (lane,bb)
                found = true;
                mydig = (u32)(4 * lane + bb);
                myk   = kq - g;
                myng  = ng + g;
                myhb  = hb;
            }
            g += hb;
        }
        u64 fm = __ballot(found);
        int src = (int)__builtin_ctzll(fm);
        pf |= ((u32)__shfl((int)mydig, src)) << shift;
        kq  = (u32)__shfl((int)myk,  src);
        ng  = (u32)__shfl((int)myng, src);
        u32 hbs = (u32)__shfl((int)myhb, src);
        if (kq == hbs) { geq = 1u; break; }  // whole bucket selected: exact
    }

    // ---- selection mask (wave-local, register state)
    const u32 uth = pf;
    u32 selm = 0u;
    if (geq) {
#pragma unroll
        for (int i = 0; i < 32; ++i)
            if (uk[i] >= uth) selm |= 1u << i;
    } else {
        const u32 quota = (u32)TOPK_ - ng;
        u32 eqm = 0u;
#pragma unroll
        for (int i = 0; i < 32; ++i) {
            u32 u = uk[i];
            if (u > uth) selm |= 1u << i;
            else if (u == uth) eqm |= 1u << i;
        }
        u32 ec = (u32)__builtin_popcount(eqm);
        for (int off = 1; off < 64; off <<= 1) ec += __shfl_xor(ec, off);
        if (ec == quota) {
            selm |= eqm;                 // common case: take all tied entries
        } else {                         // rare: rank ties by lowest index j
            u32 base = 0;
            u64 lmask = ((u64)1 << lane) - 1;
#pragma unroll
            for (int i = 0; i < 32; ++i) {
                u64 mm = __ballot((eqm >> i) & 1u);
                if ((eqm >> i) & 1u) {
                    u32 rk = base + (u32)__builtin_popcountll(mm & lmask);
                    if (rk < quota) selm |= 1u << i;
                }
                base += (u32)__builtin_popcountll(mm);
            }
        }
    }

    // ---- wave-local softmax (mrow from the min/max reduction), invZ in P
    float z = 0.f;
#pragma unroll
    for (int i = 0; i < 32; ++i) {
        float vv = fkeyinv((uk[i] >> sh) + ulo);          // exact inverse
        float e = ((selm >> i) & 1u) ? __expf(vv - mrow) : 0.f;
        uk[i] = __float_as_uint(e);      // keys dead; reuse as e-storage
        z += e;
    }
    for (int off = 1; off < 64; off <<= 1) z += __shfl_xor(z, off);
    float invZ = 1.0f / z;

    // ---- prefetch kc0 V tiles (L2 loads overlap the P barriers)
    const unsigned short* vt = VT + (size_t)(b * KVH_ + kvh) * DH_ * L_;
    const int jb0 = w * 128 + quad * 8;
    s8v pv0 = *(const s8v*)(vt + (size_t)( 0 + col) * L_ + jb0);
    s8v pv1 = *(const s8v*)(vt + (size_t)(16 + col) * L_ + jb0);
    s8v pv2 = *(const s8v*)(vt + (size_t)(32 + col) * L_ + jb0);
    s8v pv3 = *(const s8v*)(vt + (size_t)(48 + col) * L_ + jb0);

    // ---- P -> Pc (bf16, invZ folded); row w
    __syncthreads();                     // hist use done; Pc region free
#pragma unroll
    for (int i = 0; i < 32; ++i) {
        unsigned short pv16 = bf16rne(__uint_as_float(uk[i]) * invZ);
        Pc[w * 2072 + 1024 * (i >> 4) + 64 * (i & 15) + lane] = pv16;
    }
    __syncthreads();                     // all P rows written

    // ---- PV via MFMA; wave w covers j in [128w, 128w+128) in 4 sub-chunks
    f4v acc0 = {0.f, 0.f, 0.f, 0.f}, acc1 = acc0, acc2 = acc0, acc3 = acc0;
    {
        s8v ap = *(const s8v*)&Pc[col * 2072 + jb0];
        acc0 = MFMA16(ap, pv0, acc0);
        acc1 = MFMA16(ap, pv1, acc1);
        acc2 = MFMA16(ap, pv2, acc2);
        acc3 = MFMA16(ap, pv3, acc3);
    }
#pragma unroll
    for (int kc = 1; kc < 4; ++kc) {
        int jb = w * 128 + kc * 32 + quad * 8;
        s8v ap = *(const s8v*)&Pc[col * 2072 + jb];
        s8v v0 = *(const s8v*)(vt + (size_t)( 0 + col) * L_ + jb);
        s8v v1 = *(const s8v*)(vt + (size_t)(16 + col) * L_ + jb);
        s8v v2 = *(const s8v*)(vt + (size_t)(32 + col) * L_ + jb);
        s8v v3 = *(const s8v*)(vt + (size_t)(48 + col) * L_ + jb);
        acc0 = MFMA16(ap, v0, acc0);
        acc1 = MFMA16(ap, v1, acc1);
        acc2 = MFMA16(ap, v2, acc2);
        acc3 = MFMA16(ap, v3, acc3);
    }

    // ---- cross-wave PV reduction (all 16 rows live) + store as bf16 hi/lo
    // into the dead K/V columns of QKV (row m*4096 us, AOh at +2048, AOl +3072)
#pragma unroll
    for (int r = 0; r < 4; ++r) {
        atomicAdd(&outred[(quad * 4 + r) * 68 +  0 + col], acc0[r]);
        atomicAdd(&outred[(quad * 4 + r) * 68 + 16 + col], acc1[r]);
        atomicAdd(&outred[(quad * 4 + r) * 68 + 32 + col], acc2[r]);
        atomicAdd(&outred[(quad * 4 + r) * 68 + 48 + col], acc3[r]);
    }
    __syncthreads();
    if (t < 256) {
        int q = t >> 4, d4 = (t & 15) * 4;
        float4 o = *(float4*)&outred[q * 68 + d4];
        size_t m = (size_t)(b * L_ + l0 + (q & 7));
        int n = (kvh * 2 + (q >> 3)) * DH_ + d4;
        float x[4] = {o.x, o.y, o.z, o.w};
        us4 hv, lv;
#pragma unroll
        for (int i = 0; i < 4; ++i) {
            unsigned short hi = bf16rne(x[i]);
            hv[i] = hi;
            lv[i] = bf16rne(x[i] - bf2f(hi));
        }
        *(us4*)(AOus + m * 4096 + 2048 + n) = hv;
        *(us4*)(AOus + m * 4096 + 3072 + n) = lv;
    }
}

// ---------------------------------------------------------------------------
extern "C" void kernel_launch(void* const* d_in, const int* in_sizes, int n_in,
                              void* d_out, int out_size, void* d_ws, size_t ws_size,
                              hipStream_t stream) {
    const float* hs = (const float*)d_in[0];
    const float* wq = (const float*)d_in[1];
    const float* wk = (const float*)d_in[2];
    const float* wv = (const float*)d_in[3];
    const float* wo = (const float*)d_in[4];
    const int*  pos = (const int*)d_in[5];

    float* ws = (float*)d_ws;
    const size_t M1 = 1u << 20;
    float* QKV = ws;                           // [0, 8M) fp32 [4096][2048]
                                               // cols 0..1023 Q; 1024.. K|V,
                                               // later overwritten by AO hi/lo
    unsigned short* QKVWh = (unsigned short*)(ws +  8 * M1);  // [2048][1024]
    unsigned short* QKVWl = (unsigned short*)(ws +  9 * M1);
    unsigned short* WoH   = (unsigned short*)(ws + 10 * M1);
    unsigned short* WoL   = (unsigned short*)(ws + 10 * M1 + M1 / 2);
    unsigned short* KH    = (unsigned short*)(ws + 11 * M1);
    unsigned short* KL    = (unsigned short*)(ws + 12 * M1);
    unsigned short* VT    = (unsigned short*)(ws + 13 * M1);
    // hs pre-split overlays KH/KL/VT (dead until prep_k/prep_v, which run
    // after the QKV gemm consumes hsH/hsL)
    unsigned short* hsH   = (unsigned short*)(ws + 11 * M1);  // [4096][1024]
    unsigned short* hsL   = (unsigned short*)(ws + 13 * M1);
    float* out = (float*)d_out;

    static bool attr_set = false;
    if (!attr_set) {
        hipFuncSetAttribute((const void*)attn,
                            hipFuncAttributeMaxDynamicSharedMemorySize, 139904);
        attr_set = true;
    }

    dim3 blk(256);
    // fused Q|K|V weights: rows 0..1023 Wq, 1024..1535 Wk, 1536..2047 Wv
    prep_wt<<<dim3(16, 16), blk, 0, stream>>>(wq, QKVWh, QKVWl, 1024, 1024);
    prep_wt<<<dim3(16,  8), blk, 0, stream>>>(wk, QKVWh + (size_t)1024 * 1024,
                                              QKVWl + (size_t)1024 * 1024, 1024, 512);
    prep_wt<<<dim3(16,  8), blk, 0, stream>>>(wv, QKVWh + (size_t)1536 * 1024,
                                              QKVWl + (size_t)1536 * 1024, 1024, 512);
    prep_wt<<<dim3(16, 16), blk, 0, stream>>>(wo, WoH, WoL, 1024, 1024);
    split_a<<<dim3(4096), blk, 0, stream>>>(hs, hsH, hsL);
    // fused QKV projection: one N=2048 gemm, 512 blocks
    gemm_bf<<<dim3(32, 16), blk, 0, stream>>>(hsH, hsL, 1024, QKVWh, QKVWl,
                                              QKV, 1024, 2048);
    rope_q<<<dim3(8192), blk, 0, stream>>>(QKV, pos);
    prep_k<<<dim3(8192), blk, 0, stream>>>(QKV, KH, KL, pos);
    prep_v<<<dim3(512),  blk, 0, stream>>>(QKV, VT);
    attn<<<dim3(4096), dim3(1024), 139904, stream>>>(QKV, KH, KL, VT,
                                                     (unsigned short*)QKV);
    // final projection: A = AO bf16 hi/lo packed in QKV upper columns
    gemm_bf<<<dim3(32, 8), blk, 0, stream>>>((unsigned short*)QKV + 2048,
                                             (unsigned short*)QKV + 3072, 4096,
                                             WoH, WoL, out, 1024, 1024);
}

// Round 10
// 824.122 us; speedup vs baseline: 1.4579x; 1.2630x over previous
//
#include <hip/hip_runtime.h>
#include <cstdint>
#include <cstddef>

typedef unsigned int u32;
typedef unsigned long long u64;
typedef __attribute__((ext_vector_type(8))) short s8v;   // 8 bf16 (4 VGPRs)
typedef __attribute__((ext_vector_type(4))) float f4v;   // MFMA C/D
typedef __attribute__((ext_vector_type(4))) unsigned short us4;

#define B_   2
#define L_   2048
#define D_   1024
#define NH_  16
#define KVH_ 8
#define DH_  64
#define TOPK_ 1024

#define MFMA16(a, b, c) __builtin_amdgcn_mfma_f32_16x16x32_bf16(a, b, c, 0, 0, 0)

// order-preserving float->uint key (descending float == descending uint)
__device__ __forceinline__ u32 fkey(float s) {
    u32 b = __float_as_uint(s);
    return b ^ ((u32)((int)b >> 31) | 0x80000000u);
}
// exact inverse of fkey
__device__ __forceinline__ float fkeyinv(u32 k) {
    u32 b = (k & 0x80000000u) ? (k ^ 0x80000000u) : ~k;
    return __uint_as_float(b);
}
// fp32 -> bf16 round-to-nearest-even, as raw ushort
__device__ __forceinline__ unsigned short bf16rne(float x) {
    u32 u = __float_as_uint(x);
    u32 r = (u + 0x7FFFu + ((u >> 16) & 1u)) >> 16;
    return (unsigned short)r;
}
__device__ __forceinline__ float bf2f(unsigned short h) {
    return __uint_as_float((u32)h << 16);
}

// ---------------------------------------------------------------------------
// W [K][N] fp32 -> WtH/WtL [N][K] bf16 hi/lo (transpose + split). grid (K/64, N/64)
// ---------------------------------------------------------------------------
__global__ __launch_bounds__(256) void prep_wt(const float* __restrict__ W,
                                               unsigned short* __restrict__ WtH,
                                               unsigned short* __restrict__ WtL,
                                               int K, int N) {
    __shared__ float tile[64 * 65];
    int k0 = blockIdx.x * 64, n0 = blockIdx.y * 64;
    int t = threadIdx.x;
#pragma unroll
    for (int i = 0; i < 16; ++i) {
        int idx = t + i * 256;
        int kk = idx >> 6, nn = idx & 63;
        tile[kk * 65 + nn] = W[(size_t)(k0 + kk) * N + n0 + nn];
    }
    __syncthreads();
#pragma unroll
    for (int i = 0; i < 16; ++i) {
        int idx = t + i * 256;
        int nn = idx >> 6, kk = idx & 63;
        float x = tile[kk * 65 + nn];
        unsigned short hi = bf16rne(x);
        unsigned short lo = bf16rne(x - bf2f(hi));
        WtH[(size_t)(n0 + nn) * K + k0 + kk] = hi;
        WtL[(size_t)(n0 + nn) * K + k0 + kk] = lo;
    }
}

// ---------------------------------------------------------------------------
// A [M][K] fp32 -> AH/AL bf16 hi/lo (same layout). 4 elems/thread.
// ---------------------------------------------------------------------------
__global__ __launch_bounds__(256) void split_a(const float* __restrict__ A,
                                               unsigned short* __restrict__ AH,
                                               unsigned short* __restrict__ AL) {
    size_t tid = (size_t)blockIdx.x * 256 + threadIdx.x;
    float4 v = *(const float4*)(A + tid * 4);
    us4 hv, lv;
    float x[4] = {v.x, v.y, v.z, v.w};
#pragma unroll
    for (int i = 0; i < 4; ++i) {
        unsigned short hi = bf16rne(x[i]);
        hv[i] = hi;
        lv[i] = bf16rne(x[i] - bf2f(hi));
    }
    *(us4*)(AH + tid * 4) = hv;
    *(us4*)(AL + tid * 4) = lv;
}

// ---------------------------------------------------------------------------
// MFMA GEMM, bf16-A variant: C[M][N] fp32 = A(hi/lo bf16, row stride lda)
// @ Wt([N][K] bf16 hi/lo), 3-term hi/lo. BM=BN=128, BK=32; 256 thr.
// grid (M/128, N/128), XCD-chunked swizzle (nwg%8==0).
// ---------------------------------------------------------------------------
__global__ __launch_bounds__(256) void gemm_bf(
    const unsigned short* __restrict__ Ah,
    const unsigned short* __restrict__ Al,
    int lda,
    const unsigned short* __restrict__ Wh,
    const unsigned short* __restrict__ Wl,
    float* __restrict__ C, int K, int N) {
    __shared__ __align__(16) unsigned short lAh[128 * 40];
    __shared__ __align__(16) unsigned short lAl[128 * 40];
    __shared__ __align__(16) unsigned short lBh[128 * 40];
    __shared__ __align__(16) unsigned short lBl[128 * 40];
    const int t = threadIdx.x, lane = t & 63, w = t >> 6;
    const int quad = lane >> 4, col = lane & 15;
    const int wm = w >> 1, wn = w & 1;
    const int nwg = gridDim.x * gridDim.y;
    const int lin = blockIdx.y * gridDim.x + blockIdx.x;
    const int swz = (lin & 7) * (nwg >> 3) + (lin >> 3);
    const int bx = swz % gridDim.x, by = swz / gridDim.x;
    const int m0 = bx * 128, n0 = by * 128;
    const int sr = t >> 1, sk = (t & 1) * 16;

    f4v acc[4][4];
#pragma unroll
    for (int i = 0; i < 4; ++i)
#pragma unroll
        for (int j = 0; j < 4; ++j) acc[i][j] = (f4v){0.f, 0.f, 0.f, 0.f};

    for (int k0 = 0; k0 < K; k0 += 32) {
        const unsigned short* ap = Ah + (size_t)(m0 + sr) * lda + k0 + sk;
        const unsigned short* alp = Al + (size_t)(m0 + sr) * lda + k0 + sk;
        s8v a_h0 = *(const s8v*)(ap);
        s8v a_h1 = *(const s8v*)(ap + 8);
        s8v a_l0 = *(const s8v*)(alp);
        s8v a_l1 = *(const s8v*)(alp + 8);
        s8v bh0 = *(const s8v*)(Wh + (size_t)(n0 + sr) * K + k0 + sk);
        s8v bh1 = *(const s8v*)(Wh + (size_t)(n0 + sr) * K + k0 + sk + 8);
        s8v bl0 = *(const s8v*)(Wl + (size_t)(n0 + sr) * K + k0 + sk);
        s8v bl1 = *(const s8v*)(Wl + (size_t)(n0 + sr) * K + k0 + sk + 8);
        __syncthreads();
        *(s8v*)&lAh[sr * 40 + sk]     = a_h0;
        *(s8v*)&lAh[sr * 40 + sk + 8] = a_h1;
        *(s8v*)&lAl[sr * 40 + sk]     = a_l0;
        *(s8v*)&lAl[sr * 40 + sk + 8] = a_l1;
        *(s8v*)&lBh[sr * 40 + sk]     = bh0;
        *(s8v*)&lBh[sr * 40 + sk + 8] = bh1;
        *(s8v*)&lBl[sr * 40 + sk]     = bl0;
        *(s8v*)&lBl[sr * 40 + sk + 8] = bl1;
        __syncthreads();
        s8v amh[4], aml[4], bnh[4], bnl[4];
#pragma unroll
        for (int mt = 0; mt < 4; ++mt) {
            amh[mt] = *(s8v*)&lAh[(wm * 64 + mt * 16 + col) * 40 + quad * 8];
            aml[mt] = *(s8v*)&lAl[(wm * 64 + mt * 16 + col) * 40 + quad * 8];
        }
#pragma unroll
        for (int nt = 0; nt < 4; ++nt) {
            bnh[nt] = *(s8v*)&lBh[(wn * 64 + nt * 16 + col) * 40 + quad * 8];
            bnl[nt] = *(s8v*)&lBl[(wn * 64 + nt * 16 + col) * 40 + quad * 8];
        }
#pragma unroll
        for (int mt = 0; mt < 4; ++mt)
#pragma unroll
            for (int nt = 0; nt < 4; ++nt) {
                acc[mt][nt] = MFMA16(amh[mt], bnh[nt], acc[mt][nt]);
                acc[mt][nt] = MFMA16(amh[mt], bnl[nt], acc[mt][nt]);
                acc[mt][nt] = MFMA16(aml[mt], bnh[nt], acc[mt][nt]);
            }
    }
#pragma unroll
    for (int mt = 0; mt < 4; ++mt)
#pragma unroll
        for (int nt = 0; nt < 4; ++nt)
#pragma unroll
            for (int r = 0; r < 4; ++r)
                C[(size_t)(m0 + wm * 64 + mt * 16 + quad * 4 + r) * N +
                  n0 + wn * 64 + nt * 16 + col] = acc[mt][nt][r];
}

// ---------------------------------------------------------------------------
// RoPE on Q, in place. Q in fused QKV buffer: row stride 2048, cols 0..1023.
// ---------------------------------------------------------------------------
__global__ __launch_bounds__(256) void rope_q(float* __restrict__ Q,
                                              const int* __restrict__ pos) {
    int tid = blockIdx.x * 256 + threadIdx.x;
    int dl = tid & 31;
    int h  = (tid >> 5) & 15;
    int l  = (tid >> 9) & 2047;
    int b  = tid >> 20;
    size_t base = (size_t)(b * L_ + l) * 2048 + h * DH_;
    float x1 = Q[base + dl];
    float x2 = Q[base + dl + 32];
    float p = (float)pos[b * L_ + l];
    float invf = (float)pow(10000.0, -(double)dl / 32.0);
    float a = p * invf;
    float s, c;
    sincosf(a, &s, &c);
    Q[base + dl]      = x1 * c - x2 * s;
    Q[base + dl + 32] = x2 * c + x1 * s;
}

// ---------------------------------------------------------------------------
// RoPE on K + hi/lo bf16 split. K in fused QKV: row stride 2048, col
// 1024 + kvh*64 + d. Output layout [b][kvh][l][d].
// ---------------------------------------------------------------------------
__global__ __launch_bounds__(256) void prep_k(const float* __restrict__ QKV,
                                              unsigned short* __restrict__ KHp,
                                              unsigned short* __restrict__ KLp,
                                              const int* __restrict__ pos) {
    int tid = blockIdx.x * 256 + threadIdx.x;
    int d   = tid & 63;
    int l   = (tid >> 6) & 2047;
    int kvh = (tid >> 17) & 7;
    int b   = tid >> 20;
    size_t src = (size_t)(b * L_ + l) * 2048 + 1024 + kvh * DH_;
    float x  = QKV[src + d];
    int dp   = (d < 32) ? d + 32 : d - 32;
    float xp = QKV[src + dp];
    float p = (float)pos[b * L_ + l];
    int i = d & 31;
    float invf = (float)pow(10000.0, -(double)i / 32.0);
    float a = p * invf;
    float s, c;
    sincosf(a, &s, &c);
    float out = (d < 32) ? (x * c - xp * s) : (x * c + xp * s);
    unsigned short hi = bf16rne(out);
    unsigned short lo = bf16rne(out - bf2f(hi));
    size_t dst = ((size_t)(b * KVH_ + kvh) * L_ + l) * DH_ + d;
    KHp[dst] = hi;
    KLp[dst] = lo;
}

// ---------------------------------------------------------------------------
// V transpose to bf16 from fused QKV (V at col 1536 + kvh*64 + d, stride 2048)
// -> VT[b][kvh][d][l]
// ---------------------------------------------------------------------------
__global__ __launch_bounds__(256) void prep_v(const float* __restrict__ QKV,
                                              unsigned short* __restrict__ VTp) {
    __shared__ float tile[64 * 65];
    int bid = blockIdx.x;
    int lb  = bid & 31;
    int kvh = (bid >> 5) & 7;
    int b   = bid >> 8;
    int l0  = lb * 64;
    int t   = threadIdx.x;
#pragma unroll
    for (int i = 0; i < 16; ++i) {
        int idx = t + i * 256;
        int ll = idx >> 6, d = idx & 63;
        tile[ll * 65 + d] =
            QKV[(size_t)(b * L_ + l0 + ll) * 2048 + 1536 + kvh * DH_ + d];
    }
    __syncthreads();
#pragma unroll
    for (int i = 0; i < 16; ++i) {
        int idx = t + i * 256;
        int d = idx >> 6, ll = idx & 63;
        VTp[((size_t)(b * KVH_ + kvh) * DH_ + d) * L_ + l0 + ll] = bf16rne(tile[ll * 65 + d]);
    }
}

// ---------------------------------------------------------------------------
// Fused sparse attention, R18: 512-thread / 8-wave blocks, 2 blocks/CU.
// Post-R17: attn block-slot (53us) >> bottom-up cost (~15us): at 1 block/CU
// every barrier drains all waves, so each phase's stall class (QK: L2 lat;
// middle: shfl/atomic chains; PV: L2 lat) runs unmixed. Restore R8's
// 2-independent-blocks overlap WITHOUT giving back the R14 merge: 8 waves,
// still 16 real q-rows (wave owns rows 2w,2w+1; ukA[32]+ukB[32] ~64 regs fits
// 128-reg budget at 4 waves/SIMD). LDS 78.8KB: Sc halved (2 J-passes),
// Pc unions Sc, hist 1x-repl in its OWN region (stays live across the two
// sequential middles), qtile unions outred -> 2 blocks/CU = 2 barrier
// domains. Falsifier: attn flat ~850 -> per-wave chain floor dominates.
// ---------------------------------------------------------------------------
__global__ __launch_bounds__(512, 4) void attn(
    const float* __restrict__ QR,
    const unsigned short* __restrict__ KH,
    const unsigned short* __restrict__ KL,
    const unsigned short* __restrict__ VT,
    unsigned short* __restrict__ AOus) {

    extern __shared__ __align__(16) unsigned char dynsm[];
    float* Sc = (float*)dynsm;                     // [16][1034] f32 = 66176B
    unsigned short* Pc = (unsigned short*)dynsm;   // [16][2072] us = 66304B (union)
    u32* hist = (u32*)(dynsm + 66304);             // [8][256] u32 = 8192B
    float* qtile  = (float*)(dynsm + 74496);       // [16][68] f32 = 4352B
    float* outred = (float*)(dynsm + 74496);       // union w/ qtile (dead after A-frags)

    const int t = threadIdx.x;                     // 0..511
    const int lane = t & 63, w = t >> 6;           // w in [0,8)
    const int quad = lane >> 4, col = lane & 15;
    // XCD-chunked remap (bijective: 4096 % 8 == 0)
    const int bid0 = blockIdx.x;
    const int bid  = (bid0 & 7) * 512 + (bid0 >> 3);
    const int l0  = (bid & 255) * 8;
    const int kvh = (bid >> 8) & 7;
    const int b   = bid >> 11;
    const int r0 = 2 * w, r1 = 2 * w + 1;          // q-rows owned by this wave

    // ---- load Q tile (16 rows = 8 l-pos x heads {2kvh, 2kvh+1})
    if (t < 256) {
        int q = t >> 4, d4 = (t & 15) * 4;
        *(float4*)&qtile[q * 68 + d4] =
            *(const float4*)(QR + (size_t)(b * L_ + l0 + (q & 7)) * 2048 +
                             (kvh * 2 + (q >> 3)) * DH_ + d4);
    }
    __syncthreads();

    // ---- build A-frags (hi/lo): A[m=col][k=ks*32+quad*8+i]; all 16 rows real
    union FR { s8v v; unsigned short u[8]; };
    FR ah[2], al[2];
#pragma unroll
    for (int ks = 0; ks < 2; ++ks)
#pragma unroll
        for (int i = 0; i < 8; ++i) {
            float x = qtile[col * 68 + ks * 32 + quad * 8 + i];
            unsigned short hi = bf16rne(x);
            ah[ks].u[i] = hi;
            al[ks].u[i] = bf16rne(x - bf2f(hi));
        }

    // ---- QK^T in 2 J-halves of 1024 cols (wave slice 128 cols = 8 tj/half)
    const size_t slabK = (size_t)(b * KVH_ + kvh) * L_ * DH_;
    const unsigned short* khp = KH + slabK;
    const unsigned short* klp = KL + slabK;
    u32 ukA[32], ukB[32];   // keys: elem i <-> j = 1024*(i>>4) + 64*(i&15) + lane

#pragma unroll
    for (int half = 0; half < 2; ++half) {
        if (half) __syncthreads();       // half0 reads done before rewrite
#pragma unroll
        for (int tj = 0; tj < 8; ++tj) {
            int jl = w * 128 + tj * 16;  // col within half
            int j0 = half * 1024 + jl;   // global col
            const unsigned short* kh8 = khp + (size_t)(j0 + col) * 64 + quad * 8;
            const unsigned short* kl8 = klp + (size_t)(j0 + col) * 64 + quad * 8;
            s8v bh0 = *(const s8v*)(kh8);
            s8v bh1 = *(const s8v*)(kh8 + 32);
            s8v bl0 = *(const s8v*)(kl8);
            s8v bl1 = *(const s8v*)(kl8 + 32);
            f4v c = {0.f, 0.f, 0.f, 0.f};
            c = MFMA16(ah[0].v, bh0, c);
            c = MFMA16(al[0].v, bh0, c);
            c = MFMA16(ah[0].v, bl0, c);
            c = MFMA16(ah[1].v, bh1, c);
            c = MFMA16(al[1].v, bh1, c);
            c = MFMA16(ah[1].v, bl1, c);
            c = c * 0.125f;              // DH^-0.5
#pragma unroll
            for (int r = 0; r < 4; ++r)
                Sc[(quad * 4 + r) * 1034 + jl + col] = c[r];
        }
        __syncthreads();                 // Sc(half) complete
        if (half == 0) {                 // qtile dead; zero outred (union)
            outred[t] = 0.f;
            outred[t + 512] = 0.f;
            if (t < 64) outred[1024 + t] = 0.f;
        }
#pragma unroll
        for (int i2 = 0; i2 < 16; ++i2) {
            ukA[half * 16 + i2] = fkey(Sc[r0 * 1034 + i2 * 64 + lane]);
            ukB[half * 16 + i2] = fkey(Sc[r1 * 1034 + i2 * 64 + lane]);
        }
    }
    __syncthreads();                     // all Sc reads done; region free (Pc)

    // ---- wave-local middle (norm + radix top-1024 + softmax), per row.
    // hist region is per-wave and separate from Sc/Pc so it can stay hot
    // across both rows with no barriers.
    u32* hq = &hist[w * 256];
    auto middle = [&](u32 (&uk)[32]) -> float {
        // order-preserving normalization
        u32 ulo = 0xFFFFFFFFu, uhi = 0u;
#pragma unroll
        for (int i = 0; i < 32; ++i) {
            u32 u = uk[i];
            ulo = (u < ulo) ? u : ulo;
            uhi = (u > uhi) ? u : uhi;
        }
        for (int off = 1; off < 64; off <<= 1) {
            u32 ol = (u32)__shfl_xor((int)ulo, off);
            u32 oh = (u32)__shfl_xor((int)uhi, off);
            ulo = (ol < ulo) ? ol : ulo;
            uhi = (oh > uhi) ? oh : uhi;
        }
        const float mrow = fkeyinv(uhi);
        const int sh = __clz((int)((uhi - ulo) | 1u));
#pragma unroll
        for (int i = 0; i < 32; ++i) uk[i] = (uk[i] - ulo) << sh;

        // radix with wave-uniform early-exit (1x hist: hq[(d&3)*64 + (d>>2)])
        u32 pf = 0u, kq = (u32)TOPK_, ng = 0u, geq = 0u;
        for (int pass = 0; pass < 4; ++pass) {
            int shift = 24 - 8 * pass;
#pragma unroll
            for (int i = 0; i < 4; ++i) hq[i * 64 + lane] = 0u;
            u32 pm = pass ? (0xFFFFFFFFu << (shift + 8)) : 0u;
#pragma unroll
            for (int i = 0; i < 32; ++i) {
                u32 u = uk[i];
                if ((u & pm) == pf) {
                    u32 d = (u >> shift) & 255u;
                    atomicAdd(&hq[(d & 3) * 64 + (d >> 2)], 1u);
                }
            }
            u32 h0 = hq[0 * 64 + lane], h1 = hq[1 * 64 + lane];
            u32 h2 = hq[2 * 64 + lane], h3 = hq[3 * 64 + lane];
            u32 s4 = h0 + h1 + h2 + h3;
            u32 v = s4;
            for (int off = 1; off < 64; off <<= 1) {
                u32 tmp = __shfl_down(v, off);
                if (lane + off < 64) v += tmp;
            }
            u32 g = v - s4;
            u32 hb_[4] = {h0, h1, h2, h3};
            u32 mydig = 0u, myk = 0u, myng = 0u, myhb = 0u;
            bool found = false;
#pragma unroll
            for (int bb = 3; bb >= 0; --bb) {
                u32 hb = hb_[bb];
                if (hb && g < kq && kq <= g + hb) {
                    found = true;
                    mydig = (u32)(4 * lane + bb);
                    myk   = kq - g;
                    myng  = ng + g;
                    myhb  = hb;
                }
                g += hb;
            }
            u64 fm = __ballot(found);
            int src = (int)__builtin_ctzll(fm);
            pf |= ((u32)__shfl((int)mydig, src)) << shift;
            kq  = (u32)__shfl((int)myk,  src);
            ng  = (u32)__shfl((int)myng, src);
            u32 hbs = (u32)__shfl((int)myhb, src);
            if (kq == hbs) { geq = 1u; break; }
        }

        // selection mask
        const u32 uth = pf;
        u32 selm = 0u;
        if (geq) {
#pragma unroll
            for (int i = 0; i < 32; ++i)
                if (uk[i] >= uth) selm |= 1u << i;
        } else {
            const u32 quota = (u32)TOPK_ - ng;
            u32 eqm = 0u;
#pragma unroll
            for (int i = 0; i < 32; ++i) {
                u32 u = uk[i];
                if (u > uth) selm |= 1u << i;
                else if (u == uth) eqm |= 1u << i;
            }
            u32 ec = (u32)__builtin_popcount(eqm);
            for (int off = 1; off < 64; off <<= 1) ec += __shfl_xor(ec, off);
            if (ec == quota) {
                selm |= eqm;
            } else {
                u32 base = 0;
                u64 lmask = ((u64)1 << lane) - 1;
#pragma unroll
                for (int i = 0; i < 32; ++i) {
                    u64 mm = __ballot((eqm >> i) & 1u);
                    if ((eqm >> i) & 1u) {
                        u32 rk = base + (u32)__builtin_popcountll(mm & lmask);
                        if (rk < quota) selm |= 1u << i;
                    }
                    base += (u32)__builtin_popcountll(mm);
                }
            }
        }

        // softmax: e into uk, return invZ
        float z = 0.f;
#pragma unroll
        for (int i = 0; i < 32; ++i) {
            float vv = fkeyinv((uk[i] >> sh) + ulo);      // exact inverse
            float e = ((selm >> i) & 1u) ? __expf(vv - mrow) : 0.f;
            uk[i] = __float_as_uint(e);
            z += e;
        }
        for (int off = 1; off < 64; off <<= 1) z += __shfl_xor(z, off);
        return 1.0f / z;
    };

    float invZA = middle(ukA);
    float invZB = middle(ukB);

    // ---- prefetch kc0 V tiles (L2 loads overlap the P writes/barrier)
    const unsigned short* vt = VT + (size_t)(b * KVH_ + kvh) * DH_ * L_;
    const int jb0 = w * 256 + quad * 8;
    s8v pv0 = *(const s8v*)(vt + (size_t)( 0 + col) * L_ + jb0);
    s8v pv1 = *(const s8v*)(vt + (size_t)(16 + col) * L_ + jb0);
    s8v pv2 = *(const s8v*)(vt + (size_t)(32 + col) * L_ + jb0);
    s8v pv3 = *(const s8v*)(vt + (size_t)(48 + col) * L_ + jb0);

    // ---- P -> Pc (bf16, invZ folded); rows r0, r1. Pc[row][j], j packed
    // identically to uk element mapping.
#pragma unroll
    for (int i = 0; i < 32; ++i) {
        int jp = 1024 * (i >> 4) + 64 * (i & 15) + lane;
        Pc[r0 * 2072 + jp] = bf16rne(__uint_as_float(ukA[i]) * invZA);
        Pc[r1 * 2072 + jp] = bf16rne(__uint_as_float(ukB[i]) * invZB);
    }
    __syncthreads();                     // all P rows written

    // ---- PV via MFMA; wave w covers j in [256w, 256w+256) in 8 sub-chunks
    f4v acc0 = {0.f, 0.f, 0.f, 0.f}, acc1 = acc0, acc2 = acc0, acc3 = acc0;
    {
        s8v ap = *(const s8v*)&Pc[col * 2072 + jb0];
        acc0 = MFMA16(ap, pv0, acc0);
        acc1 = MFMA16(ap, pv1, acc1);
        acc2 = MFMA16(ap, pv2, acc2);
        acc3 = MFMA16(ap, pv3, acc3);
    }
#pragma unroll
    for (int kc = 1; kc < 8; ++kc) {
        int jb = w * 256 + kc * 32 + quad * 8;
        s8v ap = *(const s8v*)&Pc[col * 2072 + jb];
        s8v v0 = *(const s8v*)(vt + (size_t)( 0 + col) * L_ + jb);
        s8v v1 = *(const s8v*)(vt + (size_t)(16 + col) * L_ + jb);
        s8v v2 = *(const s8v*)(vt + (size_t)(32 + col) * L_ + jb);
        s8v v3 = *(const s8v*)(vt + (size_t)(48 + col) * L_ + jb);
        acc0 = MFMA16(ap, v0, acc0);
        acc1 = MFMA16(ap, v1, acc1);
        acc2 = MFMA16(ap, v2, acc2);
        acc3 = MFMA16(ap, v3, acc3);
    }

    // ---- cross-wave PV reduction (all 16 rows live) + store as bf16 hi/lo
#pragma unroll
    for (int r = 0; r < 4; ++r) {
        atomicAdd(&outred[(quad * 4 + r) * 68 +  0 + col], acc0[r]);
        atomicAdd(&outred[(quad * 4 + r) * 68 + 16 + col], acc1[r]);
        atomicAdd(&outred[(quad * 4 + r) * 68 + 32 + col], acc2[r]);
        atomicAdd(&outred[(quad * 4 + r) * 68 + 48 + col], acc3[r]);
    }
    __syncthreads();
    if (t < 256) {
        int q = t >> 4, d4 = (t & 15) * 4;
        float4 o = *(float4*)&outred[q * 68 + d4];
        size_t m = (size_t)(b * L_ + l0 + (q & 7));
        int n = (kvh * 2 + (q >> 3)) * DH_ + d4;
        float x[4] = {o.x, o.y, o.z, o.w};
        us4 hv, lv;
#pragma unroll
        for (int i = 0; i < 4; ++i) {
            unsigned short hi = bf16rne(x[i]);
            hv[i] = hi;
            lv[i] = bf16rne(x[i] - bf2f(hi));
        }
        *(us4*)(AOus + m * 4096 + 2048 + n) = hv;
        *(us4*)(AOus + m * 4096 + 3072 + n) = lv;
    }
}

// ---------------------------------------------------------------------------
extern "C" void kernel_launch(void* const* d_in, const int* in_sizes, int n_in,
                              void* d_out, int out_size, void* d_ws, size_t ws_size,
                              hipStream_t stream) {
    const float* hs = (const float*)d_in[0];
    const float* wq = (const float*)d_in[1];
    const float* wk = (const float*)d_in[2];
    const float* wv = (const float*)d_in[3];
    const float* wo = (const float*)d_in[4];
    const int*  pos = (const int*)d_in[5];

    float* ws = (float*)d_ws;
    const size_t M1 = 1u << 20;
    float* QKV = ws;                           // [0, 8M) fp32 [4096][2048]
    unsigned short* QKVWh = (unsigned short*)(ws +  8 * M1);  // [2048][1024]
    unsigned short* QKVWl = (unsigned short*)(ws +  9 * M1);
    unsigned short* WoH   = (unsigned short*)(ws + 10 * M1);
    unsigned short* WoL   = (unsigned short*)(ws + 10 * M1 + M1 / 2);
    unsigned short* KH    = (unsigned short*)(ws + 11 * M1);
    unsigned short* KL    = (unsigned short*)(ws + 12 * M1);
    unsigned short* VT    = (unsigned short*)(ws + 13 * M1);
    // hs pre-split overlays KH/KL/VT (dead until prep_k/prep_v)
    unsigned short* hsH   = (unsigned short*)(ws + 11 * M1);  // [4096][1024]
    unsigned short* hsL   = (unsigned short*)(ws + 13 * M1);
    float* out = (float*)d_out;

    static bool attr_set = false;
    if (!attr_set) {
        hipFuncSetAttribute((const void*)attn,
                            hipFuncAttributeMaxDynamicSharedMemorySize, 78848);
        attr_set = true;
    }

    dim3 blk(256);
    // fused Q|K|V weights: rows 0..1023 Wq, 1024..1535 Wk, 1536..2047 Wv
    prep_wt<<<dim3(16, 16), blk, 0, stream>>>(wq, QKVWh, QKVWl, 1024, 1024);
    prep_wt<<<dim3(16,  8), blk, 0, stream>>>(wk, QKVWh + (size_t)1024 * 1024,
                                              QKVWl + (size_t)1024 * 1024, 1024, 512);
    prep_wt<<<dim3(16,  8), blk, 0, stream>>>(wv, QKVWh + (size_t)1536 * 1024,
                                              QKVWl + (size_t)1536 * 1024, 1024, 512);
    prep_wt<<<dim3(16, 16), blk, 0, stream>>>(wo, WoH, WoL, 1024, 1024);
    split_a<<<dim3(4096), blk, 0, stream>>>(hs, hsH, hsL);
    gemm_bf<<<dim3(32, 16), blk, 0, stream>>>(hsH, hsL, 1024, QKVWh, QKVWl,
                                              QKV, 1024, 2048);
    rope_q<<<dim3(8192), blk, 0, stream>>>(QKV, pos);
    prep_k<<<dim3(8192), blk, 0, stream>>>(QKV, KH, KL, pos);
    prep_v<<<dim3(512),  blk, 0, stream>>>(QKV, VT);
    attn<<<dim3(4096), dim3(512), 78848, stream>>>(QKV, KH, KL, VT,
                                                   (unsigned short*)QKV);
    gemm_bf<<<dim3(32, 8), blk, 0, stream>>>((unsigned short*)QKV + 2048,
                                             (unsigned short*)QKV + 3072, 4096,
                                             WoH, WoL, out, 1024, 1024);
}